// Round 1
// 4335.622 us; speedup vs baseline: 1.1559x; 1.1559x over previous
//
#include <hip/hip_runtime.h>
#include <cmath>

typedef __bf16 bf16_t;
typedef bf16_t bf16x8 __attribute__((ext_vector_type(8)));
typedef bf16_t bf16x4 __attribute__((ext_vector_type(4)));
typedef float floatx4 __attribute__((ext_vector_type(4)));

#define B_ 2
#define T_ 1024
#define D_ 1024
#define H_ 16
#define DH_ 64
#define L_ 6
#define F_ 4096
#define V_ 32000
#define NTOK (B_ * T_)  // 2048

// ---------------------------------------------------------------- dtype detect
__global__ __launch_bounds__(256) void detect_kernel(
    const unsigned short* __restrict__ tok, int* __restrict__ flag)
{
  __shared__ int cnt;
  if (threadIdx.x == 0) cnt = 0;
  __syncthreads();
  int c = 0;
#pragma unroll
  for (int i = 0; i < 16; i++) {
    unsigned short h = tok[threadIdx.x * 16 + i];
    int e = (h >> 7) & 0xFF;
    if (e >= 134) c++;
  }
  atomicAdd(&cnt, c);
  __syncthreads();
  if (threadIdx.x == 0) *flag = (cnt > 64) ? 1 : 0;
}

// dual-dtype loaders for EXTERNAL float tensors (element indexing)
__device__ inline bf16x8 load8(const void* p, size_t i, int fp32m) {
  bf16x8 r;
  if (fp32m) {
    const float* f = (const float*)p + i;
    float4 v0 = *(const float4*)f;
    float4 v1 = *(const float4*)(f + 4);
    r[0] = (bf16_t)v0.x; r[1] = (bf16_t)v0.y; r[2] = (bf16_t)v0.z; r[3] = (bf16_t)v0.w;
    r[4] = (bf16_t)v1.x; r[5] = (bf16_t)v1.y; r[6] = (bf16_t)v1.z; r[7] = (bf16_t)v1.w;
  } else {
    r = *(const bf16x8*)((const bf16_t*)p + i);
  }
  return r;
}

__device__ inline float loadf(const void* p, size_t i, int fp32m) {
  return fp32m ? ((const float*)p)[i] : (float)((const bf16_t*)p)[i];
}

// ---------------------------------------------------------------- weight conversion
// flat: dst[i] = (bf16)src[i], n multiple of 2048
__global__ __launch_bounds__(256) void convflat_kernel(
    const void* __restrict__ src, bf16_t* __restrict__ dst,
    const int* __restrict__ modep, long n)
{
  int fp32m = *modep;
  size_t i = ((size_t)blockIdx.x * 256 + threadIdx.x) * 8;
  if ((long)i >= n) return;
  bf16x8 r = load8(src, i, fp32m);
  *(bf16x8*)(dst + i) = r;
}

// interleave wq/wk/wv -> dst[l][3][D*D]
__global__ __launch_bounds__(256) void convqkv_kernel(
    const void* __restrict__ wq, const void* __restrict__ wk,
    const void* __restrict__ wv, bf16_t* __restrict__ dst,
    const int* __restrict__ modep)
{
  int fp32m = *modep;
  size_t i = ((size_t)blockIdx.x * 256 + threadIdx.x) * 8;
  const size_t per = (size_t)D_ * D_;  // 1048576
  int lm = (int)(i / per);             // 0..17
  size_t off = i - (size_t)lm * per;
  int l = lm / 3, mat = lm - l * 3;
  const void* src = (mat == 0) ? wq : ((mat == 1) ? wk : wv);
  bf16x8 r = load8(src, (size_t)l * per + off, fp32m);
  *(bf16x8*)(dst + i) = r;
}

// ---------------------------------------------------------------- embed
__global__ __launch_bounds__(256) void embed_kernel(
    const int* __restrict__ idx, const void* __restrict__ tok,
    const void* __restrict__ pos, float* __restrict__ x,
    const int* __restrict__ modep)
{
  int fp32m = *modep;
  int row = blockIdx.x;            // b*T + t
  int t = row & (T_ - 1);
  int tokid = idx[row];
  int c = threadIdx.x * 4;
  float tv[4], pv[4];
  if (fp32m) {
    float4 a = *(const float4*)((const float*)tok + (size_t)tokid * D_ + c);
    float4 b = *(const float4*)((const float*)pos + (size_t)t * D_ + c);
    tv[0] = a.x; tv[1] = a.y; tv[2] = a.z; tv[3] = a.w;
    pv[0] = b.x; pv[1] = b.y; pv[2] = b.z; pv[3] = b.w;
  } else {
    bf16x4 a = *(const bf16x4*)((const bf16_t*)tok + (size_t)tokid * D_ + c);
    bf16x4 b = *(const bf16x4*)((const bf16_t*)pos + (size_t)t * D_ + c);
#pragma unroll
    for (int j = 0; j < 4; j++) { tv[j] = (float)a[j]; pv[j] = (float)b[j]; }
  }
  float4 o;
  o.x = tv[0] + pv[0]; o.y = tv[1] + pv[1];
  o.z = tv[2] + pv[2]; o.w = tv[3] + pv[3];
  *(float4*)(x + (size_t)row * D_ + c) = o;
}

// ---------------------------------------------------------------- layernorm
__global__ __launch_bounds__(256) void ln_kernel(
    const float* __restrict__ x, const void* __restrict__ w,
    const void* __restrict__ bb, bf16_t* __restrict__ out,
    const int* __restrict__ modep, int woff)
{
  int fp32m = *modep;
  int row = blockIdx.x, tid = threadIdx.x;
  int lane = tid & 63, wid = tid >> 6;
  const float* xr = x + (size_t)row * D_;
  float4 xv = ((const float4*)xr)[tid];
  float s = xv.x + xv.y + xv.z + xv.w;
  float sq = xv.x * xv.x + xv.y * xv.y + xv.z * xv.z + xv.w * xv.w;
#pragma unroll
  for (int off = 32; off; off >>= 1) {
    s += __shfl_xor(s, off);
    sq += __shfl_xor(sq, off);
  }
  __shared__ float ss[4], ssq[4];
  if (lane == 0) { ss[wid] = s; ssq[wid] = sq; }
  __syncthreads();
  s = ss[0] + ss[1] + ss[2] + ss[3];
  sq = ssq[0] + ssq[1] + ssq[2] + ssq[3];
  float mean = s * (1.f / D_);
  float var = sq * (1.f / D_) - mean * mean;   // jnp.var: biased
  var = fmaxf(var, 0.f);
  float rstd = rsqrtf(var + 1e-5f);
  int c = tid * 4;
  float xa[4] = {xv.x, xv.y, xv.z, xv.w};
  bf16x4 ov;
#pragma unroll
  for (int j = 0; j < 4; j++) {
    float wj = loadf(w, (size_t)woff + c + j, fp32m);
    float bj = loadf(bb, (size_t)woff + c + j, fp32m);
    ov[j] = (bf16_t)((xa[j] - mean) * rstd * wj + bj);
  }
  *(bf16x4*)(out + (size_t)row * D_ + c) = ov;
}

// ---------------------------------------------------------------- gelu
__device__ inline float gelu_f(float v) {
  return 0.5f * v * (1.f + erff(v * 0.70710678118654752f));
}

// ---------------------------------------------------------------- 128x128 MFMA GEMM (bf16 weights in ws)
// C = A @ W^T, A [M,K] bf16, W [N,K] bf16. m97 structure: BK=32,
// global_load_lds width 16, linear LDS, 4 waves x (4x4) 16x16x32 frags.
__device__ inline void gload16(void* lds, const void* g) {
  __builtin_amdgcn_global_load_lds(
      (__attribute__((address_space(1))) void*)(g),
      (__attribute__((address_space(3))) void*)(lds), 16, 0, 0);
}

__global__ __launch_bounds__(256) void gemm128(
    const bf16_t* __restrict__ A, const bf16_t* __restrict__ W,
    const void* __restrict__ bias, size_t boff, const float* __restrict__ res,
    bf16_t* __restrict__ outb, float* __restrict__ outf, void* __restrict__ outx,
    const int* __restrict__ modep, int M, int N, int K, int dogelu)
{
  __shared__ __align__(16) bf16_t As[128 * 32];
  __shared__ __align__(16) bf16_t Bs[128 * 32];
  int fp32m = *modep;
  int tid = threadIdx.x;
  int lane = tid & 63, wid = tid >> 6;
  int wm = wid & 1, wn = wid >> 1;          // 2x2 waves, each 64x64 out
  int m0 = blockIdx.x * 128, n0 = blockIdx.y * 128;
  int ln15 = lane & 15, q4 = lane >> 4;
  // staging: LDS byte off = round*4096 + tid*16 -> row = round*64 + tid/4, col = (tid&3)*8
  int srow = tid >> 2;
  int scol = (tid & 3) * 8;
  const bf16_t* Ag0 = A + (size_t)(m0 + srow) * K + scol;
  const bf16_t* Ag1 = A + (size_t)(m0 + 64 + srow) * K + scol;
  const bf16_t* Wg0 = W + (size_t)(n0 + srow) * K + scol;
  const bf16_t* Wg1 = W + (size_t)(n0 + 64 + srow) * K + scol;
  bf16_t* Asp0 = &As[tid * 8];
  bf16_t* Asp1 = &As[2048 + tid * 8];
  bf16_t* Bsp0 = &Bs[tid * 8];
  bf16_t* Bsp1 = &Bs[2048 + tid * 8];
  floatx4 acc[4][4] = {};
  for (int k0 = 0; k0 < K; k0 += 32) {
    __syncthreads();
    gload16(Asp0, Ag0 + k0);
    gload16(Asp1, Ag1 + k0);
    gload16(Bsp0, Wg0 + k0);
    gload16(Bsp1, Wg1 + k0);
    __syncthreads();   // drains vmcnt -> LDS tile ready
    bf16x8 a[4], b[4];
#pragma unroll
    for (int i = 0; i < 4; i++) {
      a[i] = *(const bf16x8*)&As[(wm * 64 + i * 16 + ln15) * 32 + q4 * 8];
      b[i] = *(const bf16x8*)&Bs[(wn * 64 + i * 16 + ln15) * 32 + q4 * 8];
    }
#pragma unroll
    for (int mt = 0; mt < 4; mt++)
#pragma unroll
      for (int nt = 0; nt < 4; nt++)
        acc[mt][nt] = __builtin_amdgcn_mfma_f32_16x16x32_bf16(a[mt], b[nt], acc[mt][nt], 0, 0, 0);
  }
#pragma unroll
  for (int mt = 0; mt < 4; mt++)
#pragma unroll
    for (int nt = 0; nt < 4; nt++) {
      int col = n0 + wn * 64 + nt * 16 + ln15;
      float bv = bias ? loadf(bias, boff + col, fp32m) : 0.f;
#pragma unroll
      for (int r = 0; r < 4; r++) {
        int row = m0 + wm * 64 + mt * 16 + q4 * 4 + r;
        float v = acc[mt][nt][r] + bv;
        if (dogelu) v = gelu_f(v);
        size_t o = (size_t)row * N + col;
        if (res) v += res[o];
        if (outf) outf[o] = v;
        if (outb) outb[o] = (bf16_t)v;
        if (outx) {
          if (fp32m) ((float*)outx)[o] = v;
          else ((bf16_t*)outx)[o] = (bf16_t)v;
        }
      }
    }
}

// ---------------------------------------------------------------- legacy 64x64 GEMM (fallback, dual-dtype W)
__global__ __launch_bounds__(256) void gemm_bt(
    const bf16_t* __restrict__ A, const void* __restrict__ W, size_t woffs,
    const void* __restrict__ bias, size_t boff, const float* __restrict__ res,
    bf16_t* __restrict__ outb, float* __restrict__ outf, void* __restrict__ outx,
    const int* __restrict__ modep, int M, int N, int K, int dogelu)
{
  __shared__ __align__(16) bf16_t As[64][40];
  __shared__ __align__(16) bf16_t Bs[64][40];
  int fp32m = *modep;
  int tid = threadIdx.x;
  int lane = tid & 63, wid = tid >> 6;
  int wm = wid & 1, wn = wid >> 1;
  int m0 = blockIdx.y * 64, n0 = blockIdx.x * 64;
  int srow = tid >> 2, scol = (tid & 3) * 8;
  const bf16_t* Ap = A + (size_t)(m0 + srow) * K + scol;
  size_t wrow = woffs + (size_t)(n0 + srow) * K + scol;
  floatx4 acc[2][2] = {};
  int ln15 = lane & 15, q4 = lane >> 4;
  for (int k0 = 0; k0 < K; k0 += 32) {
    __syncthreads();
    *(bf16x8*)&As[srow][scol] = *(const bf16x8*)(Ap + k0);
    *(bf16x8*)&Bs[srow][scol] = load8(W, wrow + k0, fp32m);
    __syncthreads();
    bf16x8 a0 = *(const bf16x8*)&As[wm * 32 + ln15][q4 * 8];
    bf16x8 a1 = *(const bf16x8*)&As[wm * 32 + 16 + ln15][q4 * 8];
    bf16x8 b0 = *(const bf16x8*)&Bs[wn * 32 + ln15][q4 * 8];
    bf16x8 b1 = *(const bf16x8*)&Bs[wn * 32 + 16 + ln15][q4 * 8];
    acc[0][0] = __builtin_amdgcn_mfma_f32_16x16x32_bf16(a0, b0, acc[0][0], 0, 0, 0);
    acc[0][1] = __builtin_amdgcn_mfma_f32_16x16x32_bf16(a0, b1, acc[0][1], 0, 0, 0);
    acc[1][0] = __builtin_amdgcn_mfma_f32_16x16x32_bf16(a1, b0, acc[1][0], 0, 0, 0);
    acc[1][1] = __builtin_amdgcn_mfma_f32_16x16x32_bf16(a1, b1, acc[1][1], 0, 0, 0);
  }
#pragma unroll
  for (int mt = 0; mt < 2; mt++)
#pragma unroll
    for (int nt = 0; nt < 2; nt++) {
      int col = n0 + wn * 32 + nt * 16 + ln15;
      float bv = bias ? loadf(bias, boff + col, fp32m) : 0.f;
#pragma unroll
      for (int r = 0; r < 4; r++) {
        int row = m0 + wm * 32 + mt * 16 + q4 * 4 + r;
        float v = acc[mt][nt][r] + bv;
        if (dogelu) v = gelu_f(v);
        size_t o = (size_t)row * N + col;
        if (res) v += res[o];
        if (outf) outf[o] = v;
        if (outb) outb[o] = (bf16_t)v;
        if (outx) {
          if (fp32m) ((float*)outx)[o] = v;
          else ((bf16_t*)outx)[o] = (bf16_t)v;
        }
      }
    }
}

// ---------------------------------------------------------------- flash attention (muP 1/DH scale)
// q/k/v row stride = `stride` elements (supports fused qkv buffer); y stride = D_.
__global__ __launch_bounds__(256) void attn_kernel(
    const bf16_t* __restrict__ q, const bf16_t* __restrict__ k,
    const bf16_t* __restrict__ v, bf16_t* __restrict__ y, int stride)
{
  __shared__ float Kt[64][65];
  __shared__ float Vt[64][65];
  __shared__ float qs[4][64];
  __shared__ float ps[4][64];
  int tid = threadIdx.x;
  int lane = tid & 63, w = tid >> 6;
  int blk = blockIdx.x;
  int tqblk = blk & 255;
  int bh = blk >> 8;
  int b = bh >> 4, hh = bh & 15;
  int tq_base = tqblk * 4;
  int tq = tq_base + w;
  size_t qrow = ((size_t)(b * T_ + tq)) * stride + hh * DH_;
  qs[w][lane] = (float)q[qrow + lane];
  float m_i = -INFINITY, l_i = 0.f, acc = 0.f;
  int ntiles = (tq_base >> 6) + 1;
  int lr = tid >> 2, lc = (tid & 3) * 16;
  for (int it = 0; it < ntiles; it++) {
    int tk0 = it * 64;
    __syncthreads();
    size_t gbase = ((size_t)(b * T_ + tk0 + lr)) * stride + hh * DH_ + lc;
    bf16x8 kv0 = *(const bf16x8*)(k + gbase);
    bf16x8 kv1 = *(const bf16x8*)(k + gbase + 8);
    bf16x8 vv0 = *(const bf16x8*)(v + gbase);
    bf16x8 vv1 = *(const bf16x8*)(v + gbase + 8);
#pragma unroll
    for (int j = 0; j < 8; j++) {
      Kt[lr][lc + j] = (float)kv0[j];
      Kt[lr][lc + 8 + j] = (float)kv1[j];
      Vt[lr][lc + j] = (float)vv0[j];
      Vt[lr][lc + 8 + j] = (float)vv1[j];
    }
    __syncthreads();
    int tk = tk0 + lane;
    float s = -INFINITY;
    if (tk <= tq) {
      float a = 0.f;
#pragma unroll
      for (int d = 0; d < 64; d++) a += qs[w][d] * Kt[lane][d];
      s = a * (1.f / 64.f);  // muP: 1/d_head
    }
    float mt = s;
#pragma unroll
    for (int off = 32; off; off >>= 1) mt = fmaxf(mt, __shfl_xor(mt, off));
    float mnew = fmaxf(m_i, mt);
    float alpha = (m_i == -INFINITY) ? 0.f : expf(m_i - mnew);
    float p = (tk <= tq) ? expf(s - mnew) : 0.f;
    float psum = p;
#pragma unroll
    for (int off = 32; off; off >>= 1) psum += __shfl_xor(psum, off);
    l_i = l_i * alpha + psum;
    ps[w][lane] = p;
    float pv = 0.f;
#pragma unroll
    for (int j = 0; j < 64; j++) pv += ps[w][j] * Vt[j][lane];
    acc = acc * alpha + pv;
    m_i = mnew;
  }
  y[((size_t)(b * T_ + tq)) * D_ + hh * DH_ + lane] = (bf16_t)(acc / l_i);
}

// ---------------------------------------------------------------- host
static inline void launch_gemm128(const bf16_t* A, const bf16_t* W,
                                  const void* bias, size_t boff, const float* res,
                                  bf16_t* outb, float* outf, void* outx,
                                  const int* modep, int M, int N, int K,
                                  int dogelu, hipStream_t s)
{
  dim3 g(M / 128, N / 128);   // m fastest -> consecutive blocks share W-tile in L2
  gemm128<<<g, dim3(256), 0, s>>>(A, W, bias, boff, res, outb, outf, outx,
                                  modep, M, N, K, dogelu);
}

static inline void launch_gemm_old(const bf16_t* A, const void* W, size_t woffs,
                                   const void* bias, size_t boff, const float* res,
                                   bf16_t* outb, float* outf, void* outx,
                                   const int* modep, int M, int N, int K,
                                   int dogelu, hipStream_t s)
{
  dim3 g(N / 64, M / 64);
  gemm_bt<<<g, dim3(256), 0, s>>>(A, W, woffs, bias, boff, res, outb, outf,
                                  outx, modep, M, N, K, dogelu);
}

// workspace layout (new path)
#define OFF_X      256ull
#define OFF_H      8388864ull
#define OFF_QKV    12583168ull
#define OFF_Y      25166080ull
#define OFF_HF     29360384ull
#define OFF_WQKV   46137600ull
#define OFF_WPROJ  83886336ull
#define OFF_WFC1   96469248ull
#define OFF_WFC2   146800896ull
#define OFF_WHEAD  197132544ull
#define REQ_WS     262668544ull

extern "C" void kernel_launch(void* const* d_in, const int* in_sizes, int n_in,
                              void* d_out, int out_size, void* d_ws, size_t ws_size,
                              hipStream_t stream)
{
  (void)in_sizes; (void)n_in; (void)out_size;
  const int* idx      = (const int*)d_in[0];
  const void* tok_emb = d_in[1];
  const void* pos_emb = d_in[2];
  const void* ln1_w   = d_in[3];
  const void* ln1_b   = d_in[4];
  const void* wq      = d_in[5];
  const void* wk      = d_in[6];
  const void* wv      = d_in[7];
  const void* wproj   = d_in[8];
  const void* ln2_w   = d_in[9];
  const void* ln2_b   = d_in[10];
  const void* fc1_w   = d_in[11];
  const void* fc1_b   = d_in[12];
  const void* fc2_w   = d_in[13];
  const void* fc2_b   = d_in[14];
  const void* lnf_w   = d_in[15];
  const void* lnf_b   = d_in[16];
  const void* head_w  = d_in[17];

  char* ws = (char*)d_ws;
  int* modep = (int*)ws;
  detect_kernel<<<1, 256, 0, stream>>>((const unsigned short*)tok_emb, modep);

  if (ws_size >= REQ_WS) {
    // ---------------- fast path: bf16 weights in ws + 128x128 gload_lds GEMM
    float*  x   = (float*)(ws + OFF_X);
    bf16_t* h   = (bf16_t*)(ws + OFF_H);
    bf16_t* qkv = (bf16_t*)(ws + OFF_QKV);   // [NTOK][3072]
    bf16_t* yb  = (bf16_t*)(ws + OFF_Y);
    bf16_t* hf  = (bf16_t*)(ws + OFF_HF);
    bf16_t* wqkvb = (bf16_t*)(ws + OFF_WQKV);   // [L][3][D][D]
    bf16_t* wprjb = (bf16_t*)(ws + OFF_WPROJ);  // [L][D][D]
    bf16_t* wfc1b = (bf16_t*)(ws + OFF_WFC1);   // [L][F][D]
    bf16_t* wfc2b = (bf16_t*)(ws + OFF_WFC2);   // [L][D][F]
    bf16_t* whedb = (bf16_t*)(ws + OFF_WHEAD);  // [V][D]

    convqkv_kernel<<<9216, 256, 0, stream>>>(wq, wk, wv, wqkvb, modep);
    convflat_kernel<<<3072, 256, 0, stream>>>(wproj, wprjb, modep, (long)L_ * D_ * D_);
    convflat_kernel<<<12288, 256, 0, stream>>>(fc1_w, wfc1b, modep, (long)L_ * F_ * D_);
    convflat_kernel<<<12288, 256, 0, stream>>>(fc2_w, wfc2b, modep, (long)L_ * D_ * F_);
    convflat_kernel<<<16000, 256, 0, stream>>>(head_w, whedb, modep, (long)V_ * D_);

    embed_kernel<<<NTOK, 256, 0, stream>>>(idx, tok_emb, pos_emb, x, modep);

    for (int l = 0; l < L_; l++) {
      size_t wd = (size_t)l * D_ * D_;
      size_t wf = (size_t)l * F_ * D_;
      ln_kernel<<<NTOK, 256, 0, stream>>>(x, ln1_w, ln1_b, h, modep, l * D_);
      launch_gemm128(h, wqkvb + (size_t)l * 3 * D_ * D_, nullptr, 0, nullptr,
                     qkv, nullptr, nullptr, modep, NTOK, 3 * D_, D_, 0, stream);
      attn_kernel<<<B_ * H_ * (T_ / 4), 256, 0, stream>>>(
          qkv, qkv + D_, qkv + 2 * D_, yb, 3 * D_);
      launch_gemm128(yb, wprjb + wd, nullptr, 0, x, nullptr, x, nullptr,
                     modep, NTOK, D_, D_, 0, stream);
      ln_kernel<<<NTOK, 256, 0, stream>>>(x, ln2_w, ln2_b, h, modep, l * D_);
      launch_gemm128(h, wfc1b + wf, fc1_b, (size_t)l * F_, nullptr, hf, nullptr,
                     nullptr, modep, NTOK, F_, D_, 1, stream);
      launch_gemm128(hf, wfc2b + wf, fc2_b, (size_t)l * D_, x, nullptr, x,
                     nullptr, modep, NTOK, D_, F_, 0, stream);
    }

    ln_kernel<<<NTOK, 256, 0, stream>>>(x, lnf_w, lnf_b, h, modep, 0);
    launch_gemm128(h, whedb, nullptr, 0, nullptr, nullptr, nullptr, d_out,
                   modep, NTOK, V_, D_, 0, stream);
  } else {
    // ---------------- fallback: previous verified path
    float*  x  = (float*)(ws + 256);
    bf16_t* h  = (bf16_t*)(ws + 8388864);
    bf16_t* qb = (bf16_t*)(ws + 12583168);
    bf16_t* kb = (bf16_t*)(ws + 16777472);
    bf16_t* vb = (bf16_t*)(ws + 20971776);
    bf16_t* yb = (bf16_t*)(ws + 25166080);
    bf16_t* hf = (bf16_t*)(ws + 29360384);

    embed_kernel<<<NTOK, 256, 0, stream>>>(idx, tok_emb, pos_emb, x, modep);

    for (int l = 0; l < L_; l++) {
      size_t wd = (size_t)l * D_ * D_;
      size_t wf = (size_t)l * F_ * D_;
      ln_kernel<<<NTOK, 256, 0, stream>>>(x, ln1_w, ln1_b, h, modep, l * D_);
      launch_gemm_old(h, wq, wd, nullptr, 0, nullptr, qb, nullptr, nullptr,
                      modep, NTOK, D_, D_, 0, stream);
      launch_gemm_old(h, wk, wd, nullptr, 0, nullptr, kb, nullptr, nullptr,
                      modep, NTOK, D_, D_, 0, stream);
      launch_gemm_old(h, wv, wd, nullptr, 0, nullptr, vb, nullptr, nullptr,
                      modep, NTOK, D_, D_, 0, stream);
      attn_kernel<<<B_ * H_ * (T_ / 4), 256, 0, stream>>>(qb, kb, vb, yb, D_);
      launch_gemm_old(yb, wproj, wd, nullptr, 0, x, nullptr, x, nullptr,
                      modep, NTOK, D_, D_, 0, stream);
      ln_kernel<<<NTOK, 256, 0, stream>>>(x, ln2_w, ln2_b, h, modep, l * D_);
      launch_gemm_old(h, fc1_w, wf, fc1_b, (size_t)l * F_, nullptr, hf, nullptr,
                      nullptr, modep, NTOK, F_, D_, 1, stream);
      launch_gemm_old(hf, fc2_w, wf, fc2_b, (size_t)l * D_, x, nullptr, x,
                      nullptr, modep, NTOK, D_, F_, 0, stream);
    }

    ln_kernel<<<NTOK, 256, 0, stream>>>(x, lnf_w, lnf_b, h, modep, 0);
    launch_gemm_old(h, head_w, 0, nullptr, 0, nullptr, nullptr, nullptr, d_out,
                    modep, NTOK, V_, D_, 0, stream);
  }
}

// Round 2
// 2644.122 us; speedup vs baseline: 1.8953x; 1.6397x over previous
//
#include <hip/hip_runtime.h>
#include <cmath>

typedef __bf16 bf16_t;
typedef bf16_t bf16x8 __attribute__((ext_vector_type(8)));
typedef bf16_t bf16x4 __attribute__((ext_vector_type(4)));
typedef float floatx4 __attribute__((ext_vector_type(4)));

#define B_ 2
#define T_ 1024
#define D_ 1024
#define H_ 16
#define DH_ 64
#define L_ 6
#define F_ 4096
#define V_ 32000
#define NTOK (B_ * T_)  // 2048

// ---------------------------------------------------------------- dtype detect
__global__ __launch_bounds__(256) void detect_kernel(
    const unsigned short* __restrict__ tok, int* __restrict__ flag)
{
  __shared__ int cnt;
  if (threadIdx.x == 0) cnt = 0;
  __syncthreads();
  int c = 0;
#pragma unroll
  for (int i = 0; i < 16; i++) {
    unsigned short h = tok[threadIdx.x * 16 + i];
    int e = (h >> 7) & 0xFF;
    if (e >= 134) c++;
  }
  atomicAdd(&cnt, c);
  __syncthreads();
  if (threadIdx.x == 0) *flag = (cnt > 64) ? 1 : 0;
}

// dual-dtype loaders for EXTERNAL float tensors (element indexing)
__device__ inline bf16x8 load8(const void* p, size_t i, int fp32m) {
  bf16x8 r;
  if (fp32m) {
    const float* f = (const float*)p + i;
    float4 v0 = *(const float4*)f;
    float4 v1 = *(const float4*)(f + 4);
    r[0] = (bf16_t)v0.x; r[1] = (bf16_t)v0.y; r[2] = (bf16_t)v0.z; r[3] = (bf16_t)v0.w;
    r[4] = (bf16_t)v1.x; r[5] = (bf16_t)v1.y; r[6] = (bf16_t)v1.z; r[7] = (bf16_t)v1.w;
  } else {
    r = *(const bf16x8*)((const bf16_t*)p + i);
  }
  return r;
}

__device__ inline float loadf(const void* p, size_t i, int fp32m) {
  return fp32m ? ((const float*)p)[i] : (float)((const bf16_t*)p)[i];
}

// ---------------------------------------------------------------- weight conversion
__global__ __launch_bounds__(256) void convflat_kernel(
    const void* __restrict__ src, bf16_t* __restrict__ dst,
    const int* __restrict__ modep, long n)
{
  int fp32m = *modep;
  size_t i = ((size_t)blockIdx.x * 256 + threadIdx.x) * 8;
  if ((long)i >= n) return;
  bf16x8 r = load8(src, i, fp32m);
  *(bf16x8*)(dst + i) = r;
}

// interleave wq/wk/wv -> dst[l][3][D*D]
__global__ __launch_bounds__(256) void convqkv_kernel(
    const void* __restrict__ wq, const void* __restrict__ wk,
    const void* __restrict__ wv, bf16_t* __restrict__ dst,
    const int* __restrict__ modep)
{
  int fp32m = *modep;
  size_t i = ((size_t)blockIdx.x * 256 + threadIdx.x) * 8;
  const size_t per = (size_t)D_ * D_;  // 1048576
  int lm = (int)(i / per);             // 0..17
  size_t off = i - (size_t)lm * per;
  int l = lm / 3, mat = lm - l * 3;
  const void* src = (mat == 0) ? wq : ((mat == 1) ? wk : wv);
  bf16x8 r = load8(src, (size_t)l * per + off, fp32m);
  *(bf16x8*)(dst + i) = r;
}

// ---------------------------------------------------------------- embed
__global__ __launch_bounds__(256) void embed_kernel(
    const int* __restrict__ idx, const void* __restrict__ tok,
    const void* __restrict__ pos, float* __restrict__ x,
    const int* __restrict__ modep)
{
  int fp32m = *modep;
  int row = blockIdx.x;            // b*T + t
  int t = row & (T_ - 1);
  int tokid = idx[row];
  int c = threadIdx.x * 4;
  float tv[4], pv[4];
  if (fp32m) {
    float4 a = *(const float4*)((const float*)tok + (size_t)tokid * D_ + c);
    float4 b = *(const float4*)((const float*)pos + (size_t)t * D_ + c);
    tv[0] = a.x; tv[1] = a.y; tv[2] = a.z; tv[3] = a.w;
    pv[0] = b.x; pv[1] = b.y; pv[2] = b.z; pv[3] = b.w;
  } else {
    bf16x4 a = *(const bf16x4*)((const bf16_t*)tok + (size_t)tokid * D_ + c);
    bf16x4 b = *(const bf16x4*)((const bf16_t*)pos + (size_t)t * D_ + c);
#pragma unroll
    for (int j = 0; j < 4; j++) { tv[j] = (float)a[j]; pv[j] = (float)b[j]; }
  }
  float4 o;
  o.x = tv[0] + pv[0]; o.y = tv[1] + pv[1];
  o.z = tv[2] + pv[2]; o.w = tv[3] + pv[3];
  *(float4*)(x + (size_t)row * D_ + c) = o;
}

// ---------------------------------------------------------------- layernorm
__global__ __launch_bounds__(256) void ln_kernel(
    const float* __restrict__ x, const void* __restrict__ w,
    const void* __restrict__ bb, bf16_t* __restrict__ out,
    const int* __restrict__ modep, int woff)
{
  int fp32m = *modep;
  int row = blockIdx.x, tid = threadIdx.x;
  int lane = tid & 63, wid = tid >> 6;
  const float* xr = x + (size_t)row * D_;
  float4 xv = ((const float4*)xr)[tid];
  float s = xv.x + xv.y + xv.z + xv.w;
  float sq = xv.x * xv.x + xv.y * xv.y + xv.z * xv.z + xv.w * xv.w;
#pragma unroll
  for (int off = 32; off; off >>= 1) {
    s += __shfl_xor(s, off);
    sq += __shfl_xor(sq, off);
  }
  __shared__ float ss[4], ssq[4];
  if (lane == 0) { ss[wid] = s; ssq[wid] = sq; }
  __syncthreads();
  s = ss[0] + ss[1] + ss[2] + ss[3];
  sq = ssq[0] + ssq[1] + ssq[2] + ssq[3];
  float mean = s * (1.f / D_);
  float var = sq * (1.f / D_) - mean * mean;   // jnp.var: biased
  var = fmaxf(var, 0.f);
  float rstd = rsqrtf(var + 1e-5f);
  int c = tid * 4;
  float xa[4] = {xv.x, xv.y, xv.z, xv.w};
  bf16x4 ov;
#pragma unroll
  for (int j = 0; j < 4; j++) {
    float wj = loadf(w, (size_t)woff + c + j, fp32m);
    float bj = loadf(bb, (size_t)woff + c + j, fp32m);
    ov[j] = (bf16_t)((xa[j] - mean) * rstd * wj + bj);
  }
  *(bf16x4*)(out + (size_t)row * D_ + c) = ov;
}

// ---------------------------------------------------------------- gelu
__device__ inline float gelu_f(float v) {
  return 0.5f * v * (1.f + erff(v * 0.70710678118654752f));
}

// ---------------------------------------------------------------- 128x128 MFMA GEMM (bf16 weights in ws)
__device__ inline void gload16(void* lds, const void* g) {
  __builtin_amdgcn_global_load_lds(
      (__attribute__((address_space(1))) void*)(g),
      (__attribute__((address_space(3))) void*)(lds), 16, 0, 0);
}

__global__ __launch_bounds__(256) void gemm128(
    const bf16_t* __restrict__ A, const bf16_t* __restrict__ W,
    const void* __restrict__ bias, size_t boff, const float* __restrict__ res,
    bf16_t* __restrict__ outb, float* __restrict__ outf, void* __restrict__ outx,
    const int* __restrict__ modep, int M, int N, int K, int dogelu)
{
  __shared__ __align__(16) bf16_t As[128 * 32];
  __shared__ __align__(16) bf16_t Bs[128 * 32];
  int fp32m = *modep;
  int tid = threadIdx.x;
  int lane = tid & 63, wid = tid >> 6;
  int wm = wid & 1, wn = wid >> 1;          // 2x2 waves, each 64x64 out
  int m0 = blockIdx.x * 128, n0 = blockIdx.y * 128;
  int ln15 = lane & 15, q4 = lane >> 4;
  int srow = tid >> 2;
  int scol = (tid & 3) * 8;
  const bf16_t* Ag0 = A + (size_t)(m0 + srow) * K + scol;
  const bf16_t* Ag1 = A + (size_t)(m0 + 64 + srow) * K + scol;
  const bf16_t* Wg0 = W + (size_t)(n0 + srow) * K + scol;
  const bf16_t* Wg1 = W + (size_t)(n0 + 64 + srow) * K + scol;
  bf16_t* Asp0 = &As[tid * 8];
  bf16_t* Asp1 = &As[2048 + tid * 8];
  bf16_t* Bsp0 = &Bs[tid * 8];
  bf16_t* Bsp1 = &Bs[2048 + tid * 8];
  floatx4 acc[4][4] = {};
  for (int k0 = 0; k0 < K; k0 += 32) {
    __syncthreads();
    gload16(Asp0, Ag0 + k0);
    gload16(Asp1, Ag1 + k0);
    gload16(Bsp0, Wg0 + k0);
    gload16(Bsp1, Wg1 + k0);
    __syncthreads();   // drains vmcnt -> LDS tile ready
    bf16x8 a[4], b[4];
#pragma unroll
    for (int i = 0; i < 4; i++) {
      a[i] = *(const bf16x8*)&As[(wm * 64 + i * 16 + ln15) * 32 + q4 * 8];
      b[i] = *(const bf16x8*)&Bs[(wn * 64 + i * 16 + ln15) * 32 + q4 * 8];
    }
#pragma unroll
    for (int mt = 0; mt < 4; mt++)
#pragma unroll
      for (int nt = 0; nt < 4; nt++)
        acc[mt][nt] = __builtin_amdgcn_mfma_f32_16x16x32_bf16(a[mt], b[nt], acc[mt][nt], 0, 0, 0);
  }
#pragma unroll
  for (int mt = 0; mt < 4; mt++)
#pragma unroll
    for (int nt = 0; nt < 4; nt++) {
      int col = n0 + wn * 64 + nt * 16 + ln15;
      float bv = bias ? loadf(bias, boff + col, fp32m) : 0.f;
#pragma unroll
      for (int r = 0; r < 4; r++) {
        int row = m0 + wm * 64 + mt * 16 + q4 * 4 + r;
        float v = acc[mt][nt][r] + bv;
        if (dogelu) v = gelu_f(v);
        size_t o = (size_t)row * N + col;
        if (res) v += res[o];
        if (outf) outf[o] = v;
        if (outb) outb[o] = (bf16_t)v;
        if (outx) {
          if (fp32m) ((float*)outx)[o] = v;
          else ((bf16_t*)outx)[o] = (bf16_t)v;
        }
      }
    }
}

// ---------------------------------------------------------------- legacy 64x64 GEMM (fallback, dual-dtype W)
__global__ __launch_bounds__(256) void gemm_bt(
    const bf16_t* __restrict__ A, const void* __restrict__ W, size_t woffs,
    const void* __restrict__ bias, size_t boff, const float* __restrict__ res,
    bf16_t* __restrict__ outb, float* __restrict__ outf, void* __restrict__ outx,
    const int* __restrict__ modep, int M, int N, int K, int dogelu)
{
  __shared__ __align__(16) bf16_t As[64][40];
  __shared__ __align__(16) bf16_t Bs[64][40];
  int fp32m = *modep;
  int tid = threadIdx.x;
  int lane = tid & 63, wid = tid >> 6;
  int wm = wid & 1, wn = wid >> 1;
  int m0 = blockIdx.y * 64, n0 = blockIdx.x * 64;
  int srow = tid >> 2, scol = (tid & 3) * 8;
  const bf16_t* Ap = A + (size_t)(m0 + srow) * K + scol;
  size_t wrow = woffs + (size_t)(n0 + srow) * K + scol;
  floatx4 acc[2][2] = {};
  int ln15 = lane & 15, q4 = lane >> 4;
  for (int k0 = 0; k0 < K; k0 += 32) {
    __syncthreads();
    *(bf16x8*)&As[srow][scol] = *(const bf16x8*)(Ap + k0);
    *(bf16x8*)&Bs[srow][scol] = load8(W, wrow + k0, fp32m);
    __syncthreads();
    bf16x8 a0 = *(const bf16x8*)&As[wm * 32 + ln15][q4 * 8];
    bf16x8 a1 = *(const bf16x8*)&As[wm * 32 + 16 + ln15][q4 * 8];
    bf16x8 b0 = *(const bf16x8*)&Bs[wn * 32 + ln15][q4 * 8];
    bf16x8 b1 = *(const bf16x8*)&Bs[wn * 32 + 16 + ln15][q4 * 8];
    acc[0][0] = __builtin_amdgcn_mfma_f32_16x16x32_bf16(a0, b0, acc[0][0], 0, 0, 0);
    acc[0][1] = __builtin_amdgcn_mfma_f32_16x16x32_bf16(a0, b1, acc[0][1], 0, 0, 0);
    acc[1][0] = __builtin_amdgcn_mfma_f32_16x16x32_bf16(a1, b0, acc[1][0], 0, 0, 0);
    acc[1][1] = __builtin_amdgcn_mfma_f32_16x16x32_bf16(a1, b1, acc[1][1], 0, 0, 0);
  }
#pragma unroll
  for (int mt = 0; mt < 2; mt++)
#pragma unroll
    for (int nt = 0; nt < 2; nt++) {
      int col = n0 + wn * 32 + nt * 16 + ln15;
      float bv = bias ? loadf(bias, boff + col, fp32m) : 0.f;
#pragma unroll
      for (int r = 0; r < 4; r++) {
        int row = m0 + wm * 32 + mt * 16 + q4 * 4 + r;
        float v = acc[mt][nt][r] + bv;
        if (dogelu) v = gelu_f(v);
        size_t o = (size_t)row * N + col;
        if (res) v += res[o];
        if (outf) outf[o] = v;
        if (outb) outb[o] = (bf16_t)v;
        if (outx) {
          if (fp32m) ((float*)outx)[o] = v;
          else ((bf16_t*)outx)[o] = (bf16_t)v;
        }
      }
    }
}

// ---------------------------------------------------------------- MFMA flash attention (muP 1/DH scale)
// 4 waves/block, QBLK=64 (16 q-rows/wave), KVBLK=64, DH=64.
// Fragment layouts identical to gemm128 (A: row=lane&15, k=(lane>>4)*8..+7;
// C/D: col=lane&15, row=(lane>>4)*4+reg). P converts C->A layout via per-wave
// LDS round-trip. V staged transposed with XOR swizzle on tok bits 3..5.
__global__ __launch_bounds__(256) void attn_mfma(
    const bf16_t* __restrict__ qkv, bf16_t* __restrict__ y)
{
  __shared__ __align__(16) bf16_t Ks[64][72];        // [tok][d], +8 pad
  __shared__ __align__(16) bf16_t Vt[64][72];        // [d][tok^swz], +8 pad
  __shared__ __align__(16) bf16_t Ps[4][16][72];     // per-wave P
  int tid = threadIdx.x;
  int lane = tid & 63, w = tid >> 6;
  int ln15 = lane & 15, g = lane >> 4;
  // heavy-first, paired scheduling: slot i gets qb=15-j, slot i+256 gets qb=j
  int idxb = blockIdx.x;
  int phase = idxb >> 8, slot = idxb & 255;
  int bh = slot >> 3, jj = slot & 7;
  int qb = phase ? jj : (15 - jj);
  int b = bh >> 4, h = bh & 15;
  int q0 = qb * 64;
  int qrow = q0 + w * 16;          // wave's q base
  const bf16_t* kp = qkv + 1024;
  const bf16_t* vp = qkv + 2048;
  // Q fragments (held in registers for the whole block)
  bf16x8 qa0, qa1;
  {
    size_t base = ((size_t)(b * T_ + qrow + ln15)) * 3072 + h * 64 + g * 8;
    qa0 = *(const bf16x8*)(qkv + base);
    qa1 = *(const bf16x8*)(qkv + base + 32);
  }
  floatx4 o[4] = {};               // O accum: d-ntiles, C-layout
  float m_i[4], l_i[4];
#pragma unroll
  for (int r = 0; r < 4; r++) { m_i[r] = -__builtin_inff(); l_i[r] = 0.f; }
  int ntile = qb + 1;
  int sr = tid >> 2, sc = (tid & 3) * 16;   // staging coords
  for (int it = 0; it < ntile; it++) {
    int k0 = it * 64;
    __syncthreads();   // previous tile's LDS reads done
    size_t gb = ((size_t)(b * T_ + k0 + sr)) * 3072 + h * 64 + sc;
    bf16x8 kv0 = *(const bf16x8*)(kp + gb);
    bf16x8 kv1 = *(const bf16x8*)(kp + gb + 8);
    bf16x8 vv0 = *(const bf16x8*)(vp + gb);
    bf16x8 vv1 = *(const bf16x8*)(vp + gb + 8);
    *(bf16x8*)&Ks[sr][sc] = kv0;
    *(bf16x8*)&Ks[sr][sc + 8] = kv1;
#pragma unroll
    for (int e = 0; e < 8; e++) {
      int d0 = sc + e, d1 = sc + 8 + e;
      Vt[d0][sr ^ (((d0 >> 3) & 7) << 3)] = vv0[e];
      Vt[d1][sr ^ (((d1 >> 3) & 7) << 3)] = vv1[e];
    }
    __syncthreads();
    // S = Q @ K^T  (4 n-tiles of 16 k-cols, 2 k-steps over d)
    floatx4 s[4] = {};
#pragma unroll
    for (int nt = 0; nt < 4; nt++) {
      bf16x8 b0 = *(const bf16x8*)&Ks[nt * 16 + ln15][g * 8];
      bf16x8 b1 = *(const bf16x8*)&Ks[nt * 16 + ln15][32 + g * 8];
      s[nt] = __builtin_amdgcn_mfma_f32_16x16x32_bf16(qa0, b0, s[nt], 0, 0, 0);
      s[nt] = __builtin_amdgcn_mfma_f32_16x16x32_bf16(qa1, b1, s[nt], 0, 0, 0);
    }
    int last = (it == ntile - 1);
    // scale + causal mask + per-row max
    float p[4][4];
    float mt[4];
#pragma unroll
    for (int r = 0; r < 4; r++) mt[r] = -__builtin_inff();
#pragma unroll
    for (int nt = 0; nt < 4; nt++)
#pragma unroll
      for (int r = 0; r < 4; r++) {
        float sv = s[nt][r] * 0.015625f;   // muP 1/d_head
        if (last && (k0 + nt * 16 + ln15) > (qrow + g * 4 + r))
          sv = -__builtin_inff();
        p[nt][r] = sv;
        mt[r] = fmaxf(mt[r], sv);
      }
#pragma unroll
    for (int off = 1; off < 16; off <<= 1)
#pragma unroll
      for (int r = 0; r < 4; r++) mt[r] = fmaxf(mt[r], __shfl_xor(mt[r], off));
    float alpha[4];
#pragma unroll
    for (int r = 0; r < 4; r++) {
      float mn = fmaxf(m_i[r], mt[r]);
      alpha[r] = __expf(m_i[r] - mn);   // exp(-inf)=0 on first tile
      m_i[r] = mn;
    }
    // P = exp(S - m), row-sum, write to per-wave LDS for layout conversion
    float rs[4] = {0.f, 0.f, 0.f, 0.f};
#pragma unroll
    for (int nt = 0; nt < 4; nt++)
#pragma unroll
      for (int r = 0; r < 4; r++) {
        float pv = __expf(p[nt][r] - m_i[r]);
        rs[r] += pv;
        Ps[w][g * 4 + r][nt * 16 + ln15] = (bf16_t)pv;
      }
#pragma unroll
    for (int off = 1; off < 16; off <<= 1)
#pragma unroll
      for (int r = 0; r < 4; r++) rs[r] += __shfl_xor(rs[r], off);
#pragma unroll
    for (int r = 0; r < 4; r++) l_i[r] = l_i[r] * alpha[r] + rs[r];
#pragma unroll
    for (int nt = 0; nt < 4; nt++)
#pragma unroll
      for (int r = 0; r < 4; r++) o[nt][r] *= alpha[r];
    // O += P @ V  (P A-frags from LDS, V B-frags from transposed Vt)
#pragma unroll
    for (int ks = 0; ks < 2; ks++) {
      bf16x8 pa = *(const bf16x8*)&Ps[w][ln15][ks * 32 + g * 8];
#pragma unroll
      for (int nt = 0; nt < 4; nt++) {
        int d = nt * 16 + ln15;
        bf16x8 vb = *(const bf16x8*)&Vt[d][(ks * 32 + g * 8) ^ (((d >> 3) & 7) << 3)];
        o[nt] = __builtin_amdgcn_mfma_f32_16x16x32_bf16(pa, vb, o[nt], 0, 0, 0);
      }
    }
  }
  // epilogue: normalize and store
#pragma unroll
  for (int nt = 0; nt < 4; nt++)
#pragma unroll
    for (int r = 0; r < 4; r++) {
      size_t orow = (size_t)(b * T_ + qrow + g * 4 + r) * D_ + h * 64 + nt * 16 + ln15;
      y[orow] = (bf16_t)(o[nt][r] / l_i[r]);
    }
}

// ---------------------------------------------------------------- legacy scalar flash attention (fallback)
__global__ __launch_bounds__(256) void attn_kernel(
    const bf16_t* __restrict__ q, const bf16_t* __restrict__ k,
    const bf16_t* __restrict__ v, bf16_t* __restrict__ y, int stride)
{
  __shared__ float Kt[64][65];
  __shared__ float Vt[64][65];
  __shared__ float qs[4][64];
  __shared__ float ps[4][64];
  int tid = threadIdx.x;
  int lane = tid & 63, w = tid >> 6;
  int blk = blockIdx.x;
  int tqblk = blk & 255;
  int bh = blk >> 8;
  int b = bh >> 4, hh = bh & 15;
  int tq_base = tqblk * 4;
  int tq = tq_base + w;
  size_t qrow = ((size_t)(b * T_ + tq)) * stride + hh * DH_;
  qs[w][lane] = (float)q[qrow + lane];
  float m_i = -INFINITY, l_i = 0.f, acc = 0.f;
  int ntiles = (tq_base >> 6) + 1;
  int lr = tid >> 2, lc = (tid & 3) * 16;
  for (int it = 0; it < ntiles; it++) {
    int tk0 = it * 64;
    __syncthreads();
    size_t gbase = ((size_t)(b * T_ + tk0 + lr)) * stride + hh * DH_ + lc;
    bf16x8 kv0 = *(const bf16x8*)(k + gbase);
    bf16x8 kv1 = *(const bf16x8*)(k + gbase + 8);
    bf16x8 vv0 = *(const bf16x8*)(v + gbase);
    bf16x8 vv1 = *(const bf16x8*)(v + gbase + 8);
#pragma unroll
    for (int j = 0; j < 8; j++) {
      Kt[lr][lc + j] = (float)kv0[j];
      Kt[lr][lc + 8 + j] = (float)kv1[j];
      Vt[lr][lc + j] = (float)vv0[j];
      Vt[lr][lc + 8 + j] = (float)vv1[j];
    }
    __syncthreads();
    int tk = tk0 + lane;
    float s = -INFINITY;
    if (tk <= tq) {
      float a = 0.f;
#pragma unroll
      for (int d = 0; d < 64; d++) a += qs[w][d] * Kt[lane][d];
      s = a * (1.f / 64.f);
    }
    float mt = s;
#pragma unroll
    for (int off = 32; off; off >>= 1) mt = fmaxf(mt, __shfl_xor(mt, off));
    float mnew = fmaxf(m_i, mt);
    float alpha = (m_i == -INFINITY) ? 0.f : expf(m_i - mnew);
    float p = (tk <= tq) ? expf(s - mnew) : 0.f;
    float psum = p;
#pragma unroll
    for (int off = 32; off; off >>= 1) psum += __shfl_xor(psum, off);
    l_i = l_i * alpha + psum;
    ps[w][lane] = p;
    float pv = 0.f;
#pragma unroll
    for (int j = 0; j < 64; j++) pv += ps[w][j] * Vt[j][lane];
    acc = acc * alpha + pv;
    m_i = mnew;
  }
  y[((size_t)(b * T_ + tq)) * D_ + hh * DH_ + lane] = (bf16_t)(acc / l_i);
}

// ---------------------------------------------------------------- host
static inline void launch_gemm128(const bf16_t* A, const bf16_t* W,
                                  const void* bias, size_t boff, const float* res,
                                  bf16_t* outb, float* outf, void* outx,
                                  const int* modep, int M, int N, int K,
                                  int dogelu, hipStream_t s)
{
  dim3 g(M / 128, N / 128);   // m fastest -> consecutive blocks share W-tile in L2
  gemm128<<<g, dim3(256), 0, s>>>(A, W, bias, boff, res, outb, outf, outx,
                                  modep, M, N, K, dogelu);
}

static inline void launch_gemm_old(const bf16_t* A, const void* W, size_t woffs,
                                   const void* bias, size_t boff, const float* res,
                                   bf16_t* outb, float* outf, void* outx,
                                   const int* modep, int M, int N, int K,
                                   int dogelu, hipStream_t s)
{
  dim3 g(N / 64, M / 64);
  gemm_bt<<<g, dim3(256), 0, s>>>(A, W, woffs, bias, boff, res, outb, outf,
                                  outx, modep, M, N, K, dogelu);
}

// workspace layout (new path)
#define OFF_X      256ull
#define OFF_H      8388864ull
#define OFF_QKV    12583168ull
#define OFF_Y      25166080ull
#define OFF_HF     29360384ull
#define OFF_WQKV   46137600ull
#define OFF_WPROJ  83886336ull
#define OFF_WFC1   96469248ull
#define OFF_WFC2   146800896ull
#define OFF_WHEAD  197132544ull
#define REQ_WS     262668544ull

extern "C" void kernel_launch(void* const* d_in, const int* in_sizes, int n_in,
                              void* d_out, int out_size, void* d_ws, size_t ws_size,
                              hipStream_t stream)
{
  (void)in_sizes; (void)n_in; (void)out_size;
  const int* idx      = (const int*)d_in[0];
  const void* tok_emb = d_in[1];
  const void* pos_emb = d_in[2];
  const void* ln1_w   = d_in[3];
  const void* ln1_b   = d_in[4];
  const void* wq      = d_in[5];
  const void* wk      = d_in[6];
  const void* wv      = d_in[7];
  const void* wproj   = d_in[8];
  const void* ln2_w   = d_in[9];
  const void* ln2_b   = d_in[10];
  const void* fc1_w   = d_in[11];
  const void* fc1_b   = d_in[12];
  const void* fc2_w   = d_in[13];
  const void* fc2_b   = d_in[14];
  const void* lnf_w   = d_in[15];
  const void* lnf_b   = d_in[16];
  const void* head_w  = d_in[17];

  char* ws = (char*)d_ws;
  int* modep = (int*)ws;
  detect_kernel<<<1, 256, 0, stream>>>((const unsigned short*)tok_emb, modep);

  if (ws_size >= REQ_WS) {
    // ---------------- fast path: bf16 weights in ws + 128x128 gload_lds GEMM
    float*  x   = (float*)(ws + OFF_X);
    bf16_t* h   = (bf16_t*)(ws + OFF_H);
    bf16_t* qkv = (bf16_t*)(ws + OFF_QKV);   // [NTOK][3072]
    bf16_t* yb  = (bf16_t*)(ws + OFF_Y);
    bf16_t* hf  = (bf16_t*)(ws + OFF_HF);
    bf16_t* wqkvb = (bf16_t*)(ws + OFF_WQKV);   // [L][3][D][D]
    bf16_t* wprjb = (bf16_t*)(ws + OFF_WPROJ);  // [L][D][D]
    bf16_t* wfc1b = (bf16_t*)(ws + OFF_WFC1);   // [L][F][D]
    bf16_t* wfc2b = (bf16_t*)(ws + OFF_WFC2);   // [L][D][F]
    bf16_t* whedb = (bf16_t*)(ws + OFF_WHEAD);  // [V][D]

    convqkv_kernel<<<9216, 256, 0, stream>>>(wq, wk, wv, wqkvb, modep);
    convflat_kernel<<<3072, 256, 0, stream>>>(wproj, wprjb, modep, (long)L_ * D_ * D_);
    convflat_kernel<<<12288, 256, 0, stream>>>(fc1_w, wfc1b, modep, (long)L_ * F_ * D_);
    convflat_kernel<<<12288, 256, 0, stream>>>(fc2_w, wfc2b, modep, (long)L_ * D_ * F_);
    convflat_kernel<<<16000, 256, 0, stream>>>(head_w, whedb, modep, (long)V_ * D_);

    embed_kernel<<<NTOK, 256, 0, stream>>>(idx, tok_emb, pos_emb, x, modep);

    for (int l = 0; l < L_; l++) {
      size_t wd = (size_t)l * D_ * D_;
      size_t wf = (size_t)l * F_ * D_;
      ln_kernel<<<NTOK, 256, 0, stream>>>(x, ln1_w, ln1_b, h, modep, l * D_);
      launch_gemm128(h, wqkvb + (size_t)l * 3 * D_ * D_, nullptr, 0, nullptr,
                     qkv, nullptr, nullptr, modep, NTOK, 3 * D_, D_, 0, stream);
      attn_mfma<<<512, 256, 0, stream>>>(qkv, yb);
      launch_gemm128(yb, wprjb + wd, nullptr, 0, x, nullptr, x, nullptr,
                     modep, NTOK, D_, D_, 0, stream);
      ln_kernel<<<NTOK, 256, 0, stream>>>(x, ln2_w, ln2_b, h, modep, l * D_);
      launch_gemm128(h, wfc1b + wf, fc1_b, (size_t)l * F_, nullptr, hf, nullptr,
                     nullptr, modep, NTOK, F_, D_, 1, stream);
      launch_gemm128(hf, wfc2b + wf, fc2_b, (size_t)l * D_, x, nullptr, x,
                     nullptr, modep, NTOK, D_, F_, 0, stream);
    }

    ln_kernel<<<NTOK, 256, 0, stream>>>(x, lnf_w, lnf_b, h, modep, 0);
    launch_gemm128(h, whedb, nullptr, 0, nullptr, nullptr, nullptr, d_out,
                   modep, NTOK, V_, D_, 0, stream);
  } else {
    // ---------------- fallback: previous verified path
    float*  x  = (float*)(ws + 256);
    bf16_t* h  = (bf16_t*)(ws + 8388864);
    bf16_t* qb = (bf16_t*)(ws + 12583168);
    bf16_t* kb = (bf16_t*)(ws + 16777472);
    bf16_t* vb = (bf16_t*)(ws + 20971776);
    bf16_t* yb = (bf16_t*)(ws + 25166080);
    bf16_t* hf = (bf16_t*)(ws + 29360384);

    embed_kernel<<<NTOK, 256, 0, stream>>>(idx, tok_emb, pos_emb, x, modep);

    for (int l = 0; l < L_; l++) {
      size_t wd = (size_t)l * D_ * D_;
      size_t wf = (size_t)l * F_ * D_;
      ln_kernel<<<NTOK, 256, 0, stream>>>(x, ln1_w, ln1_b, h, modep, l * D_);
      launch_gemm_old(h, wq, wd, nullptr, 0, nullptr, qb, nullptr, nullptr,
                      modep, NTOK, D_, D_, 0, stream);
      launch_gemm_old(h, wk, wd, nullptr, 0, nullptr, kb, nullptr, nullptr,
                      modep, NTOK, D_, D_, 0, stream);
      launch_gemm_old(h, wv, wd, nullptr, 0, nullptr, vb, nullptr, nullptr,
                      modep, NTOK, D_, D_, 0, stream);
      attn_kernel<<<B_ * H_ * (T_ / 4), 256, 0, stream>>>(qb, kb, vb, yb, D_);
      launch_gemm_old(yb, wproj, wd, nullptr, 0, x, nullptr, x, nullptr,
                      modep, NTOK, D_, D_, 0, stream);
      ln_kernel<<<NTOK, 256, 0, stream>>>(x, ln2_w, ln2_b, h, modep, l * D_);
      launch_gemm_old(h, fc1_w, wf, fc1_b, (size_t)l * F_, nullptr, hf, nullptr,
                      nullptr, modep, NTOK, F_, D_, 1, stream);
      launch_gemm_old(hf, fc2_w, wf, fc2_b, (size_t)l * D_, x, nullptr, x,
                      nullptr, modep, NTOK, D_, F_, 0, stream);
    }

    ln_kernel<<<NTOK, 256, 0, stream>>>(x, lnf_w, lnf_b, h, modep, 0);
    launch_gemm_old(h, head_w, 0, nullptr, 0, nullptr, nullptr, nullptr, d_out,
                    modep, NTOK, V_, D_, 0, stream);
  }
}

// Round 3
// 2318.596 us; speedup vs baseline: 2.1614x; 1.1404x over previous
//
#include <hip/hip_runtime.h>
#include <cmath>

typedef __bf16 bf16_t;
typedef bf16_t bf16x8 __attribute__((ext_vector_type(8)));
typedef bf16_t bf16x4 __attribute__((ext_vector_type(4)));
typedef float floatx4 __attribute__((ext_vector_type(4)));

#define B_ 2
#define T_ 1024
#define D_ 1024
#define H_ 16
#define DH_ 64
#define L_ 6
#define F_ 4096
#define V_ 32000
#define NTOK (B_ * T_)  // 2048

// ---------------------------------------------------------------- dtype detect
__global__ __launch_bounds__(256) void detect_kernel(
    const unsigned short* __restrict__ tok, int* __restrict__ flag)
{
  __shared__ int cnt;
  if (threadIdx.x == 0) cnt = 0;
  __syncthreads();
  int c = 0;
#pragma unroll
  for (int i = 0; i < 16; i++) {
    unsigned short h = tok[threadIdx.x * 16 + i];
    int e = (h >> 7) & 0xFF;
    if (e >= 134) c++;
  }
  atomicAdd(&cnt, c);
  __syncthreads();
  if (threadIdx.x == 0) *flag = (cnt > 64) ? 1 : 0;
}

// dual-dtype loaders for EXTERNAL float tensors (element indexing)
__device__ inline bf16x8 load8(const void* p, size_t i, int fp32m) {
  bf16x8 r;
  if (fp32m) {
    const float* f = (const float*)p + i;
    float4 v0 = *(const float4*)f;
    float4 v1 = *(const float4*)(f + 4);
    r[0] = (bf16_t)v0.x; r[1] = (bf16_t)v0.y; r[2] = (bf16_t)v0.z; r[3] = (bf16_t)v0.w;
    r[4] = (bf16_t)v1.x; r[5] = (bf16_t)v1.y; r[6] = (bf16_t)v1.z; r[7] = (bf16_t)v1.w;
  } else {
    r = *(const bf16x8*)((const bf16_t*)p + i);
  }
  return r;
}

__device__ inline float loadf(const void* p, size_t i, int fp32m) {
  return fp32m ? ((const float*)p)[i] : (float)((const bf16_t*)p)[i];
}

// ---------------------------------------------------------------- weight conversion
__global__ __launch_bounds__(256) void convflat_kernel(
    const void* __restrict__ src, bf16_t* __restrict__ dst,
    const int* __restrict__ modep, long n)
{
  int fp32m = *modep;
  size_t i = ((size_t)blockIdx.x * 256 + threadIdx.x) * 8;
  if ((long)i >= n) return;
  bf16x8 r = load8(src, i, fp32m);
  *(bf16x8*)(dst + i) = r;
}

// interleave wq/wk/wv -> dst[l][3][D*D]
__global__ __launch_bounds__(256) void convqkv_kernel(
    const void* __restrict__ wq, const void* __restrict__ wk,
    const void* __restrict__ wv, bf16_t* __restrict__ dst,
    const int* __restrict__ modep)
{
  int fp32m = *modep;
  size_t i = ((size_t)blockIdx.x * 256 + threadIdx.x) * 8;
  const size_t per = (size_t)D_ * D_;  // 1048576
  int lm = (int)(i / per);             // 0..17
  size_t off = i - (size_t)lm * per;
  int l = lm / 3, mat = lm - l * 3;
  const void* src = (mat == 0) ? wq : ((mat == 1) ? wk : wv);
  bf16x8 r = load8(src, (size_t)l * per + off, fp32m);
  *(bf16x8*)(dst + i) = r;
}

// ---------------------------------------------------------------- embed
__global__ __launch_bounds__(256) void embed_kernel(
    const int* __restrict__ idx, const void* __restrict__ tok,
    const void* __restrict__ pos, float* __restrict__ x,
    const int* __restrict__ modep)
{
  int fp32m = *modep;
  int row = blockIdx.x;            // b*T + t
  int t = row & (T_ - 1);
  int tokid = idx[row];
  int c = threadIdx.x * 4;
  float tv[4], pv[4];
  if (fp32m) {
    float4 a = *(const float4*)((const float*)tok + (size_t)tokid * D_ + c);
    float4 b = *(const float4*)((const float*)pos + (size_t)t * D_ + c);
    tv[0] = a.x; tv[1] = a.y; tv[2] = a.z; tv[3] = a.w;
    pv[0] = b.x; pv[1] = b.y; pv[2] = b.z; pv[3] = b.w;
  } else {
    bf16x4 a = *(const bf16x4*)((const bf16_t*)tok + (size_t)tokid * D_ + c);
    bf16x4 b = *(const bf16x4*)((const bf16_t*)pos + (size_t)t * D_ + c);
#pragma unroll
    for (int j = 0; j < 4; j++) { tv[j] = (float)a[j]; pv[j] = (float)b[j]; }
  }
  float4 o;
  o.x = tv[0] + pv[0]; o.y = tv[1] + pv[1];
  o.z = tv[2] + pv[2]; o.w = tv[3] + pv[3];
  *(float4*)(x + (size_t)row * D_ + c) = o;
}

// ---------------------------------------------------------------- layernorm
__global__ __launch_bounds__(256) void ln_kernel(
    const float* __restrict__ x, const void* __restrict__ w,
    const void* __restrict__ bb, bf16_t* __restrict__ out,
    const int* __restrict__ modep, int woff)
{
  int fp32m = *modep;
  int row = blockIdx.x, tid = threadIdx.x;
  int lane = tid & 63, wid = tid >> 6;
  const float* xr = x + (size_t)row * D_;
  float4 xv = ((const float4*)xr)[tid];
  float s = xv.x + xv.y + xv.z + xv.w;
  float sq = xv.x * xv.x + xv.y * xv.y + xv.z * xv.z + xv.w * xv.w;
#pragma unroll
  for (int off = 32; off; off >>= 1) {
    s += __shfl_xor(s, off);
    sq += __shfl_xor(sq, off);
  }
  __shared__ float ss[4], ssq[4];
  if (lane == 0) { ss[wid] = s; ssq[wid] = sq; }
  __syncthreads();
  s = ss[0] + ss[1] + ss[2] + ss[3];
  sq = ssq[0] + ssq[1] + ssq[2] + ssq[3];
  float mean = s * (1.f / D_);
  float var = sq * (1.f / D_) - mean * mean;   // jnp.var: biased
  var = fmaxf(var, 0.f);
  float rstd = rsqrtf(var + 1e-5f);
  int c = tid * 4;
  float xa[4] = {xv.x, xv.y, xv.z, xv.w};
  bf16x4 ov;
#pragma unroll
  for (int j = 0; j < 4; j++) {
    float wj = loadf(w, (size_t)woff + c + j, fp32m);
    float bj = loadf(bb, (size_t)woff + c + j, fp32m);
    ov[j] = (bf16_t)((xa[j] - mean) * rstd * wj + bj);
  }
  *(bf16x4*)(out + (size_t)row * D_ + c) = ov;
}

// ---------------------------------------------------------------- gelu
__device__ inline float gelu_f(float v) {
  return 0.5f * v * (1.f + erff(v * 0.70710678118654752f));
}

// ---------------------------------------------------------------- tiled MFMA GEMM (bf16 weights in ws)
// C = A @ W^T. 2-barrier m97 structure, global_load_lds width 16, linear LDS.
// 4 waves in 2x2; wave tile (BM/2)x(BN/2). Bijective per-XCD block remap:
// contiguous wg chunks (m-fastest) per XCD -> W-panel fetched once per XCD.
__device__ inline void gload16(void* lds, const void* g) {
  __builtin_amdgcn_global_load_lds(
      (__attribute__((address_space(1))) void*)(g),
      (__attribute__((address_space(3))) void*)(lds), 16, 0, 0);
}

template<int BM, int BN>
__global__ __launch_bounds__(256) void gemm_t(
    const bf16_t* __restrict__ A, const bf16_t* __restrict__ W,
    const void* __restrict__ bias, size_t boff, const float* __restrict__ res,
    bf16_t* __restrict__ outb, float* __restrict__ outf, void* __restrict__ outx,
    const int* __restrict__ modep, int M, int N, int K, int dogelu, int mshift)
{
  constexpr int MT = BM / 32, NT = BN / 32;   // frags per wave
  __shared__ __align__(16) bf16_t As[BM * 32];
  __shared__ __align__(16) bf16_t Bs[BN * 32];
  int fp32m = *modep;
  int tid = threadIdx.x;
  int lane = tid & 63, wid = tid >> 6;
  int wm = wid & 1, wn = wid >> 1;
  // ---- bijective XCD remap (assumes block i -> XCD i%8)
  int nwg = gridDim.x, bid = blockIdx.x;
  int qq = nwg >> 3, rr = nwg & 7;
  int xcd = bid & 7, ii = bid >> 3;
  int wg = (xcd < rr ? xcd * (qq + 1) : rr * (qq + 1) + (xcd - rr) * qq) + ii;
  int m0 = (wg & ((1 << mshift) - 1)) * BM;
  int n0 = (wg >> mshift) * BN;
  int ln15 = lane & 15, q4 = lane >> 4;
  int srow = tid >> 2, scol = (tid & 3) * 8;
  const bf16_t* Ag[BM / 64];
  const bf16_t* Wg[BN / 64];
#pragma unroll
  for (int hh = 0; hh < BM / 64; hh++)
    Ag[hh] = A + (size_t)(m0 + hh * 64 + srow) * K + scol;
#pragma unroll
  for (int hh = 0; hh < BN / 64; hh++)
    Wg[hh] = W + (size_t)(n0 + hh * 64 + srow) * K + scol;
  floatx4 acc[MT][NT] = {};
  for (int k0 = 0; k0 < K; k0 += 32) {
    __syncthreads();
#pragma unroll
    for (int hh = 0; hh < BM / 64; hh++)
      gload16(&As[hh * 2048 + tid * 8], Ag[hh] + k0);
#pragma unroll
    for (int hh = 0; hh < BN / 64; hh++)
      gload16(&Bs[hh * 2048 + tid * 8], Wg[hh] + k0);
    __syncthreads();   // drains vmcnt -> LDS tile ready
    bf16x8 a[MT], b[NT];
#pragma unroll
    for (int i = 0; i < MT; i++)
      a[i] = *(const bf16x8*)&As[(wm * (BM / 2) + i * 16 + ln15) * 32 + q4 * 8];
#pragma unroll
    for (int j = 0; j < NT; j++)
      b[j] = *(const bf16x8*)&Bs[(wn * (BN / 2) + j * 16 + ln15) * 32 + q4 * 8];
#pragma unroll
    for (int mt = 0; mt < MT; mt++)
#pragma unroll
      for (int nt = 0; nt < NT; nt++)
        acc[mt][nt] = __builtin_amdgcn_mfma_f32_16x16x32_bf16(a[mt], b[nt], acc[mt][nt], 0, 0, 0);
  }
#pragma unroll
  for (int mt = 0; mt < MT; mt++)
#pragma unroll
    for (int nt = 0; nt < NT; nt++) {
      int col = n0 + wn * (BN / 2) + nt * 16 + ln15;
      float bv = bias ? loadf(bias, boff + col, fp32m) : 0.f;
#pragma unroll
      for (int r = 0; r < 4; r++) {
        int row = m0 + wm * (BM / 2) + mt * 16 + q4 * 4 + r;
        float v = acc[mt][nt][r] + bv;
        if (dogelu) v = gelu_f(v);
        size_t o = (size_t)row * N + col;
        if (res) v += res[o];
        if (outf) outf[o] = v;
        if (outb) outb[o] = (bf16_t)v;
        if (outx) {
          if (fp32m) ((float*)outx)[o] = v;
          else ((bf16_t*)outx)[o] = (bf16_t)v;
        }
      }
    }
}

// ---------------------------------------------------------------- legacy 64x64 GEMM (fallback, dual-dtype W)
__global__ __launch_bounds__(256) void gemm_bt(
    const bf16_t* __restrict__ A, const void* __restrict__ W, size_t woffs,
    const void* __restrict__ bias, size_t boff, const float* __restrict__ res,
    bf16_t* __restrict__ outb, float* __restrict__ outf, void* __restrict__ outx,
    const int* __restrict__ modep, int M, int N, int K, int dogelu)
{
  __shared__ __align__(16) bf16_t As[64][40];
  __shared__ __align__(16) bf16_t Bs[64][40];
  int fp32m = *modep;
  int tid = threadIdx.x;
  int lane = tid & 63, wid = tid >> 6;
  int wm = wid & 1, wn = wid >> 1;
  int m0 = blockIdx.y * 64, n0 = blockIdx.x * 64;
  int srow = tid >> 2, scol = (tid & 3) * 8;
  const bf16_t* Ap = A + (size_t)(m0 + srow) * K + scol;
  size_t wrow = woffs + (size_t)(n0 + srow) * K + scol;
  floatx4 acc[2][2] = {};
  int ln15 = lane & 15, q4 = lane >> 4;
  for (int k0 = 0; k0 < K; k0 += 32) {
    __syncthreads();
    *(bf16x8*)&As[srow][scol] = *(const bf16x8*)(Ap + k0);
    *(bf16x8*)&Bs[srow][scol] = load8(W, wrow + k0, fp32m);
    __syncthreads();
    bf16x8 a0 = *(const bf16x8*)&As[wm * 32 + ln15][q4 * 8];
    bf16x8 a1 = *(const bf16x8*)&As[wm * 32 + 16 + ln15][q4 * 8];
    bf16x8 b0 = *(const bf16x8*)&Bs[wn * 32 + ln15][q4 * 8];
    bf16x8 b1 = *(const bf16x8*)&Bs[wn * 32 + 16 + ln15][q4 * 8];
    acc[0][0] = __builtin_amdgcn_mfma_f32_16x16x32_bf16(a0, b0, acc[0][0], 0, 0, 0);
    acc[0][1] = __builtin_amdgcn_mfma_f32_16x16x32_bf16(a0, b1, acc[0][1], 0, 0, 0);
    acc[1][0] = __builtin_amdgcn_mfma_f32_16x16x32_bf16(a1, b0, acc[1][0], 0, 0, 0);
    acc[1][1] = __builtin_amdgcn_mfma_f32_16x16x32_bf16(a1, b1, acc[1][1], 0, 0, 0);
  }
#pragma unroll
  for (int mt = 0; mt < 2; mt++)
#pragma unroll
    for (int nt = 0; nt < 2; nt++) {
      int col = n0 + wn * 32 + nt * 16 + ln15;
      float bv = bias ? loadf(bias, boff + col, fp32m) : 0.f;
#pragma unroll
      for (int r = 0; r < 4; r++) {
        int row = m0 + wm * 32 + mt * 16 + q4 * 4 + r;
        float v = acc[mt][nt][r] + bv;
        if (dogelu) v = gelu_f(v);
        size_t o = (size_t)row * N + col;
        if (res) v += res[o];
        if (outf) outf[o] = v;
        if (outb) outb[o] = (bf16_t)v;
        if (outx) {
          if (fp32m) ((float*)outx)[o] = v;
          else ((bf16_t*)outx)[o] = (bf16_t)v;
        }
      }
    }
}

// ---------------------------------------------------------------- MFMA flash attention (muP 1/DH scale)
__global__ __launch_bounds__(256) void attn_mfma(
    const bf16_t* __restrict__ qkv, bf16_t* __restrict__ y)
{
  __shared__ __align__(16) bf16_t Ks[64][72];        // [tok][d], +8 pad
  __shared__ __align__(16) bf16_t Vt[64][72];        // [d][tok^swz], +8 pad
  __shared__ __align__(16) bf16_t Ps[4][16][72];     // per-wave P
  int tid = threadIdx.x;
  int lane = tid & 63, w = tid >> 6;
  int ln15 = lane & 15, g = lane >> 4;
  // heavy-first, paired scheduling: slot i gets qb=15-j, slot i+256 gets qb=j
  int idxb = blockIdx.x;
  int phase = idxb >> 8, slot = idxb & 255;
  int bh = slot >> 3, jj = slot & 7;
  int qb = phase ? jj : (15 - jj);
  int b = bh >> 4, h = bh & 15;
  int q0 = qb * 64;
  int qrow = q0 + w * 16;          // wave's q base
  const bf16_t* kp = qkv + 1024;
  const bf16_t* vp = qkv + 2048;
  // Q fragments (held in registers for the whole block)
  bf16x8 qa0, qa1;
  {
    size_t base = ((size_t)(b * T_ + qrow + ln15)) * 3072 + h * 64 + g * 8;
    qa0 = *(const bf16x8*)(qkv + base);
    qa1 = *(const bf16x8*)(qkv + base + 32);
  }
  floatx4 o[4] = {};               // O accum: d-ntiles, C-layout
  float m_i[4], l_i[4];
#pragma unroll
  for (int r = 0; r < 4; r++) { m_i[r] = -__builtin_inff(); l_i[r] = 0.f; }
  int ntile = qb + 1;
  int sr = tid >> 2, sc = (tid & 3) * 16;   // staging coords
  for (int it = 0; it < ntile; it++) {
    int k0 = it * 64;
    __syncthreads();   // previous tile's LDS reads done
    size_t gb = ((size_t)(b * T_ + k0 + sr)) * 3072 + h * 64 + sc;
    bf16x8 kv0 = *(const bf16x8*)(kp + gb);
    bf16x8 kv1 = *(const bf16x8*)(kp + gb + 8);
    bf16x8 vv0 = *(const bf16x8*)(vp + gb);
    bf16x8 vv1 = *(const bf16x8*)(vp + gb + 8);
    *(bf16x8*)&Ks[sr][sc] = kv0;
    *(bf16x8*)&Ks[sr][sc + 8] = kv1;
#pragma unroll
    for (int e = 0; e < 8; e++) {
      int d0 = sc + e, d1 = sc + 8 + e;
      Vt[d0][sr ^ (((d0 >> 3) & 7) << 3)] = vv0[e];
      Vt[d1][sr ^ (((d1 >> 3) & 7) << 3)] = vv1[e];
    }
    __syncthreads();
    // S = Q @ K^T  (4 n-tiles of 16 k-cols, 2 k-steps over d)
    floatx4 s[4] = {};
#pragma unroll
    for (int nt = 0; nt < 4; nt++) {
      bf16x8 b0 = *(const bf16x8*)&Ks[nt * 16 + ln15][g * 8];
      bf16x8 b1 = *(const bf16x8*)&Ks[nt * 16 + ln15][32 + g * 8];
      s[nt] = __builtin_amdgcn_mfma_f32_16x16x32_bf16(qa0, b0, s[nt], 0, 0, 0);
      s[nt] = __builtin_amdgcn_mfma_f32_16x16x32_bf16(qa1, b1, s[nt], 0, 0, 0);
    }
    int last = (it == ntile - 1);
    // scale + causal mask + per-row max
    float p[4][4];
    float mt[4];
#pragma unroll
    for (int r = 0; r < 4; r++) mt[r] = -__builtin_inff();
#pragma unroll
    for (int nt = 0; nt < 4; nt++)
#pragma unroll
      for (int r = 0; r < 4; r++) {
        float sv = s[nt][r] * 0.015625f;   // muP 1/d_head
        if (last && (k0 + nt * 16 + ln15) > (qrow + g * 4 + r))
          sv = -__builtin_inff();
        p[nt][r] = sv;
        mt[r] = fmaxf(mt[r], sv);
      }
#pragma unroll
    for (int off = 1; off < 16; off <<= 1)
#pragma unroll
      for (int r = 0; r < 4; r++) mt[r] = fmaxf(mt[r], __shfl_xor(mt[r], off));
    float alpha[4];
#pragma unroll
    for (int r = 0; r < 4; r++) {
      float mn = fmaxf(m_i[r], mt[r]);
      alpha[r] = __expf(m_i[r] - mn);   // exp(-inf)=0 on first tile
      m_i[r] = mn;
    }
    // P = exp(S - m), row-sum, write to per-wave LDS for layout conversion
    float rs[4] = {0.f, 0.f, 0.f, 0.f};
#pragma unroll
    for (int nt = 0; nt < 4; nt++)
#pragma unroll
      for (int r = 0; r < 4; r++) {
        float pv = __expf(p[nt][r] - m_i[r]);
        rs[r] += pv;
        Ps[w][g * 4 + r][nt * 16 + ln15] = (bf16_t)pv;
      }
#pragma unroll
    for (int off = 1; off < 16; off <<= 1)
#pragma unroll
      for (int r = 0; r < 4; r++) rs[r] += __shfl_xor(rs[r], off);
#pragma unroll
    for (int r = 0; r < 4; r++) l_i[r] = l_i[r] * alpha[r] + rs[r];
#pragma unroll
    for (int nt = 0; nt < 4; nt++)
#pragma unroll
      for (int r = 0; r < 4; r++) o[nt][r] *= alpha[r];
    // O += P @ V  (P A-frags from LDS, V B-frags from transposed Vt)
#pragma unroll
    for (int ks = 0; ks < 2; ks++) {
      bf16x8 pa = *(const bf16x8*)&Ps[w][ln15][ks * 32 + g * 8];
#pragma unroll
      for (int nt = 0; nt < 4; nt++) {
        int d = nt * 16 + ln15;
        bf16x8 vb = *(const bf16x8*)&Vt[d][(ks * 32 + g * 8) ^ (((d >> 3) & 7) << 3)];
        o[nt] = __builtin_amdgcn_mfma_f32_16x16x32_bf16(pa, vb, o[nt], 0, 0, 0);
      }
    }
  }
  // epilogue: normalize and store
#pragma unroll
  for (int nt = 0; nt < 4; nt++)
#pragma unroll
    for (int r = 0; r < 4; r++) {
      size_t orow = (size_t)(b * T_ + qrow + g * 4 + r) * D_ + h * 64 + nt * 16 + ln15;
      y[orow] = (bf16_t)(o[nt][r] / l_i[r]);
    }
}

// ---------------------------------------------------------------- legacy scalar flash attention (fallback)
__global__ __launch_bounds__(256) void attn_kernel(
    const bf16_t* __restrict__ q, const bf16_t* __restrict__ k,
    const bf16_t* __restrict__ v, bf16_t* __restrict__ y, int stride)
{
  __shared__ float Kt[64][65];
  __shared__ float Vt[64][65];
  __shared__ float qs[4][64];
  __shared__ float ps[4][64];
  int tid = threadIdx.x;
  int lane = tid & 63, w = tid >> 6;
  int blk = blockIdx.x;
  int tqblk = blk & 255;
  int bh = blk >> 8;
  int b = bh >> 4, hh = bh & 15;
  int tq_base = tqblk * 4;
  int tq = tq_base + w;
  size_t qrow = ((size_t)(b * T_ + tq)) * stride + hh * DH_;
  qs[w][lane] = (float)q[qrow + lane];
  float m_i = -INFINITY, l_i = 0.f, acc = 0.f;
  int ntiles = (tq_base >> 6) + 1;
  int lr = tid >> 2, lc = (tid & 3) * 16;
  for (int it = 0; it < ntiles; it++) {
    int tk0 = it * 64;
    __syncthreads();
    size_t gbase = ((size_t)(b * T_ + tk0 + lr)) * stride + hh * DH_ + lc;
    bf16x8 kv0 = *(const bf16x8*)(k + gbase);
    bf16x8 kv1 = *(const bf16x8*)(k + gbase + 8);
    bf16x8 vv0 = *(const bf16x8*)(v + gbase);
    bf16x8 vv1 = *(const bf16x8*)(v + gbase + 8);
#pragma unroll
    for (int j = 0; j < 8; j++) {
      Kt[lr][lc + j] = (float)kv0[j];
      Kt[lr][lc + 8 + j] = (float)kv1[j];
      Vt[lr][lc + j] = (float)vv0[j];
      Vt[lr][lc + 8 + j] = (float)vv1[j];
    }
    __syncthreads();
    int tk = tk0 + lane;
    float s = -INFINITY;
    if (tk <= tq) {
      float a = 0.f;
#pragma unroll
      for (int d = 0; d < 64; d++) a += qs[w][d] * Kt[lane][d];
      s = a * (1.f / 64.f);
    }
    float mt = s;
#pragma unroll
    for (int off = 32; off; off >>= 1) mt = fmaxf(mt, __shfl_xor(mt, off));
    float mnew = fmaxf(m_i, mt);
    float alpha = (m_i == -INFINITY) ? 0.f : expf(m_i - mnew);
    float p = (tk <= tq) ? expf(s - mnew) : 0.f;
    float psum = p;
#pragma unroll
    for (int off = 32; off; off >>= 1) psum += __shfl_xor(psum, off);
    l_i = l_i * alpha + psum;
    ps[w][lane] = p;
    float pv = 0.f;
#pragma unroll
    for (int j = 0; j < 64; j++) pv += ps[w][j] * Vt[j][lane];
    acc = acc * alpha + pv;
    m_i = mnew;
  }
  y[((size_t)(b * T_ + tq)) * D_ + hh * DH_ + lane] = (bf16_t)(acc / l_i);
}

// ---------------------------------------------------------------- host
// tile selection: head/fc1 -> 128x128; qkv -> 64x128; proj/fc2 -> 64x64.
// mshift = log2(M/BM); M=2048 always.
template<int BM, int BN>
static inline void launch_gemm_t(const bf16_t* A, const bf16_t* W,
                                 const void* bias, size_t boff, const float* res,
                                 bf16_t* outb, float* outf, void* outx,
                                 const int* modep, int M, int N, int K,
                                 int dogelu, hipStream_t s)
{
  int nMB = M / BM;
  int mshift = (nMB == 16) ? 4 : ((nMB == 32) ? 5 : 31 - __builtin_clz(nMB));
  int nwg = nMB * (N / BN);
  gemm_t<BM, BN><<<dim3(nwg), dim3(256), 0, s>>>(
      A, W, bias, boff, res, outb, outf, outx, modep, M, N, K, dogelu, mshift);
}

static inline void launch_gemm_old(const bf16_t* A, const void* W, size_t woffs,
                                   const void* bias, size_t boff, const float* res,
                                   bf16_t* outb, float* outf, void* outx,
                                   const int* modep, int M, int N, int K,
                                   int dogelu, hipStream_t s)
{
  dim3 g(N / 64, M / 64);
  gemm_bt<<<g, dim3(256), 0, s>>>(A, W, woffs, bias, boff, res, outb, outf,
                                  outx, modep, M, N, K, dogelu);
}

// workspace layout (new path)
#define OFF_X      256ull
#define OFF_H      8388864ull
#define OFF_QKV    12583168ull
#define OFF_Y      25166080ull
#define OFF_HF     29360384ull
#define OFF_WQKV   46137600ull
#define OFF_WPROJ  83886336ull
#define OFF_WFC1   96469248ull
#define OFF_WFC2   146800896ull
#define OFF_WHEAD  197132544ull
#define REQ_WS     262668544ull

extern "C" void kernel_launch(void* const* d_in, const int* in_sizes, int n_in,
                              void* d_out, int out_size, void* d_ws, size_t ws_size,
                              hipStream_t stream)
{
  (void)in_sizes; (void)n_in; (void)out_size;
  const int* idx      = (const int*)d_in[0];
  const void* tok_emb = d_in[1];
  const void* pos_emb = d_in[2];
  const void* ln1_w   = d_in[3];
  const void* ln1_b   = d_in[4];
  const void* wq      = d_in[5];
  const void* wk      = d_in[6];
  const void* wv      = d_in[7];
  const void* wproj   = d_in[8];
  const void* ln2_w   = d_in[9];
  const void* ln2_b   = d_in[10];
  const void* fc1_w   = d_in[11];
  const void* fc1_b   = d_in[12];
  const void* fc2_w   = d_in[13];
  const void* fc2_b   = d_in[14];
  const void* lnf_w   = d_in[15];
  const void* lnf_b   = d_in[16];
  const void* head_w  = d_in[17];

  char* ws = (char*)d_ws;
  int* modep = (int*)ws;
  detect_kernel<<<1, 256, 0, stream>>>((const unsigned short*)tok_emb, modep);

  if (ws_size >= REQ_WS) {
    // ---------------- fast path: bf16 weights in ws + tiled gload_lds GEMM
    float*  x   = (float*)(ws + OFF_X);
    bf16_t* h   = (bf16_t*)(ws + OFF_H);
    bf16_t* qkv = (bf16_t*)(ws + OFF_QKV);   // [NTOK][3072]
    bf16_t* yb  = (bf16_t*)(ws + OFF_Y);
    bf16_t* hf  = (bf16_t*)(ws + OFF_HF);
    bf16_t* wqkvb = (bf16_t*)(ws + OFF_WQKV);   // [L][3][D][D]
    bf16_t* wprjb = (bf16_t*)(ws + OFF_WPROJ);  // [L][D][D]
    bf16_t* wfc1b = (bf16_t*)(ws + OFF_WFC1);   // [L][F][D]
    bf16_t* wfc2b = (bf16_t*)(ws + OFF_WFC2);   // [L][D][F]
    bf16_t* whedb = (bf16_t*)(ws + OFF_WHEAD);  // [V][D]

    convqkv_kernel<<<9216, 256, 0, stream>>>(wq, wk, wv, wqkvb, modep);
    convflat_kernel<<<3072, 256, 0, stream>>>(wproj, wprjb, modep, (long)L_ * D_ * D_);
    convflat_kernel<<<12288, 256, 0, stream>>>(fc1_w, wfc1b, modep, (long)L_ * F_ * D_);
    convflat_kernel<<<12288, 256, 0, stream>>>(fc2_w, wfc2b, modep, (long)L_ * D_ * F_);
    convflat_kernel<<<16000, 256, 0, stream>>>(head_w, whedb, modep, (long)V_ * D_);

    embed_kernel<<<NTOK, 256, 0, stream>>>(idx, tok_emb, pos_emb, x, modep);

    for (int l = 0; l < L_; l++) {
      size_t wd = (size_t)l * D_ * D_;
      size_t wf = (size_t)l * F_ * D_;
      ln_kernel<<<NTOK, 256, 0, stream>>>(x, ln1_w, ln1_b, h, modep, l * D_);
      launch_gemm_t<64, 128>(h, wqkvb + (size_t)l * 3 * D_ * D_, nullptr, 0,
                             nullptr, qkv, nullptr, nullptr, modep,
                             NTOK, 3 * D_, D_, 0, stream);
      attn_mfma<<<512, 256, 0, stream>>>(qkv, yb);
      launch_gemm_t<64, 64>(yb, wprjb + wd, nullptr, 0, x, nullptr, x, nullptr,
                            modep, NTOK, D_, D_, 0, stream);
      ln_kernel<<<NTOK, 256, 0, stream>>>(x, ln2_w, ln2_b, h, modep, l * D_);
      launch_gemm_t<128, 128>(h, wfc1b + wf, fc1_b, (size_t)l * F_, nullptr, hf,
                              nullptr, nullptr, modep, NTOK, F_, D_, 1, stream);
      launch_gemm_t<64, 64>(hf, wfc2b + wf, fc2_b, (size_t)l * D_, x, nullptr, x,
                            nullptr, modep, NTOK, D_, F_, 0, stream);
    }

    ln_kernel<<<NTOK, 256, 0, stream>>>(x, lnf_w, lnf_b, h, modep, 0);
    launch_gemm_t<128, 128>(h, whedb, nullptr, 0, nullptr, nullptr, nullptr,
                            d_out, modep, NTOK, V_, D_, 0, stream);
  } else {
    // ---------------- fallback: previous verified path
    float*  x  = (float*)(ws + 256);
    bf16_t* h  = (bf16_t*)(ws + 8388864);
    bf16_t* qb = (bf16_t*)(ws + 12583168);
    bf16_t* kb = (bf16_t*)(ws + 16777472);
    bf16_t* vb = (bf16_t*)(ws + 20971776);
    bf16_t* yb = (bf16_t*)(ws + 25166080);
    bf16_t* hf = (bf16_t*)(ws + 29360384);

    embed_kernel<<<NTOK, 256, 0, stream>>>(idx, tok_emb, pos_emb, x, modep);

    for (int l = 0; l < L_; l++) {
      size_t wd = (size_t)l * D_ * D_;
      size_t wf = (size_t)l * F_ * D_;
      ln_kernel<<<NTOK, 256, 0, stream>>>(x, ln1_w, ln1_b, h, modep, l * D_);
      launch_gemm_old(h, wq, wd, nullptr, 0, nullptr, qb, nullptr, nullptr,
                      modep, NTOK, D_, D_, 0, stream);
      launch_gemm_old(h, wk, wd, nullptr, 0, nullptr, kb, nullptr, nullptr,
                      modep, NTOK, D_, D_, 0, stream);
      launch_gemm_old(h, wv, wd, nullptr, 0, nullptr, vb, nullptr, nullptr,
                      modep, NTOK, D_, D_, 0, stream);
      attn_kernel<<<B_ * H_ * (T_ / 4), 256, 0, stream>>>(qb, kb, vb, yb, D_);
      launch_gemm_old(yb, wproj, wd, nullptr, 0, x, nullptr, x, nullptr,
                      modep, NTOK, D_, D_, 0, stream);
      ln_kernel<<<NTOK, 256, 0, stream>>>(x, ln2_w, ln2_b, h, modep, l * D_);
      launch_gemm_old(h, fc1_w, wf, fc1_b, (size_t)l * F_, nullptr, hf, nullptr,
                      nullptr, modep, NTOK, F_, D_, 1, stream);
      launch_gemm_old(hf, fc2_w, wf, fc2_b, (size_t)l * D_, x, nullptr, x,
                      nullptr, modep, NTOK, D_, F_, 0, stream);
    }

    ln_kernel<<<NTOK, 256, 0, stream>>>(x, lnf_w, lnf_b, h, modep, 0);
    launch_gemm_old(h, head_w, 0, nullptr, 0, nullptr, nullptr, nullptr, d_out,
                    modep, NTOK, V_, D_, 0, stream);
  }
}

// Round 4
// 2186.610 us; speedup vs baseline: 2.2919x; 1.0604x over previous
//
#include <hip/hip_runtime.h>
#include <cmath>

typedef __bf16 bf16_t;
typedef bf16_t bf16x8 __attribute__((ext_vector_type(8)));
typedef bf16_t bf16x4 __attribute__((ext_vector_type(4)));
typedef float floatx4 __attribute__((ext_vector_type(4)));

#define B_ 2
#define T_ 1024
#define D_ 1024
#define H_ 16
#define DH_ 64
#define L_ 6
#define F_ 4096
#define V_ 32000
#define NTOK (B_ * T_)  // 2048

// ---------------------------------------------------------------- dtype detect
__global__ __launch_bounds__(256) void detect_kernel(
    const unsigned short* __restrict__ tok, int* __restrict__ flag)
{
  __shared__ int cnt;
  if (threadIdx.x == 0) cnt = 0;
  __syncthreads();
  int c = 0;
#pragma unroll
  for (int i = 0; i < 16; i++) {
    unsigned short h = tok[threadIdx.x * 16 + i];
    int e = (h >> 7) & 0xFF;
    if (e >= 134) c++;
  }
  atomicAdd(&cnt, c);
  __syncthreads();
  if (threadIdx.x == 0) *flag = (cnt > 64) ? 1 : 0;
}

// dual-dtype loaders for EXTERNAL float tensors (element indexing)
__device__ inline bf16x8 load8(const void* p, size_t i, int fp32m) {
  bf16x8 r;
  if (fp32m) {
    const float* f = (const float*)p + i;
    float4 v0 = *(const float4*)f;
    float4 v1 = *(const float4*)(f + 4);
    r[0] = (bf16_t)v0.x; r[1] = (bf16_t)v0.y; r[2] = (bf16_t)v0.z; r[3] = (bf16_t)v0.w;
    r[4] = (bf16_t)v1.x; r[5] = (bf16_t)v1.y; r[6] = (bf16_t)v1.z; r[7] = (bf16_t)v1.w;
  } else {
    r = *(const bf16x8*)((const bf16_t*)p + i);
  }
  return r;
}

__device__ inline float loadf(const void* p, size_t i, int fp32m) {
  return fp32m ? ((const float*)p)[i] : (float)((const bf16_t*)p)[i];
}

// ---------------------------------------------------------------- weight conversion
__global__ __launch_bounds__(256) void convflat_kernel(
    const void* __restrict__ src, bf16_t* __restrict__ dst,
    const int* __restrict__ modep, long n)
{
  int fp32m = *modep;
  size_t i = ((size_t)blockIdx.x * 256 + threadIdx.x) * 8;
  if ((long)i >= n) return;
  bf16x8 r = load8(src, i, fp32m);
  *(bf16x8*)(dst + i) = r;
}

// interleave wq/wk/wv -> dst[l][3][D*D]
__global__ __launch_bounds__(256) void convqkv_kernel(
    const void* __restrict__ wq, const void* __restrict__ wk,
    const void* __restrict__ wv, bf16_t* __restrict__ dst,
    const int* __restrict__ modep)
{
  int fp32m = *modep;
  size_t i = ((size_t)blockIdx.x * 256 + threadIdx.x) * 8;
  const size_t per = (size_t)D_ * D_;  // 1048576
  int lm = (int)(i / per);             // 0..17
  size_t off = i - (size_t)lm * per;
  int l = lm / 3, mat = lm - l * 3;
  const void* src = (mat == 0) ? wq : ((mat == 1) ? wk : wv);
  bf16x8 r = load8(src, (size_t)l * per + off, fp32m);
  *(bf16x8*)(dst + i) = r;
}

// ---------------------------------------------------------------- embed
__global__ __launch_bounds__(256) void embed_kernel(
    const int* __restrict__ idx, const void* __restrict__ tok,
    const void* __restrict__ pos, float* __restrict__ x,
    const int* __restrict__ modep)
{
  int fp32m = *modep;
  int row = blockIdx.x;            // b*T + t
  int t = row & (T_ - 1);
  int tokid = idx[row];
  int c = threadIdx.x * 4;
  float tv[4], pv[4];
  if (fp32m) {
    float4 a = *(const float4*)((const float*)tok + (size_t)tokid * D_ + c);
    float4 b = *(const float4*)((const float*)pos + (size_t)t * D_ + c);
    tv[0] = a.x; tv[1] = a.y; tv[2] = a.z; tv[3] = a.w;
    pv[0] = b.x; pv[1] = b.y; pv[2] = b.z; pv[3] = b.w;
  } else {
    bf16x4 a = *(const bf16x4*)((const bf16_t*)tok + (size_t)tokid * D_ + c);
    bf16x4 b = *(const bf16x4*)((const bf16_t*)pos + (size_t)t * D_ + c);
#pragma unroll
    for (int j = 0; j < 4; j++) { tv[j] = (float)a[j]; pv[j] = (float)b[j]; }
  }
  float4 o;
  o.x = tv[0] + pv[0]; o.y = tv[1] + pv[1];
  o.z = tv[2] + pv[2]; o.w = tv[3] + pv[3];
  *(float4*)(x + (size_t)row * D_ + c) = o;
}

// ---------------------------------------------------------------- layernorm
__global__ __launch_bounds__(256) void ln_kernel(
    const float* __restrict__ x, const void* __restrict__ w,
    const void* __restrict__ bb, bf16_t* __restrict__ out,
    const int* __restrict__ modep, int woff)
{
  int fp32m = *modep;
  int row = blockIdx.x, tid = threadIdx.x;
  int lane = tid & 63, wid = tid >> 6;
  const float* xr = x + (size_t)row * D_;
  float4 xv = ((const float4*)xr)[tid];
  float s = xv.x + xv.y + xv.z + xv.w;
  float sq = xv.x * xv.x + xv.y * xv.y + xv.z * xv.z + xv.w * xv.w;
#pragma unroll
  for (int off = 32; off; off >>= 1) {
    s += __shfl_xor(s, off);
    sq += __shfl_xor(sq, off);
  }
  __shared__ float ss[4], ssq[4];
  if (lane == 0) { ss[wid] = s; ssq[wid] = sq; }
  __syncthreads();
  s = ss[0] + ss[1] + ss[2] + ss[3];
  sq = ssq[0] + ssq[1] + ssq[2] + ssq[3];
  float mean = s * (1.f / D_);
  float var = sq * (1.f / D_) - mean * mean;   // jnp.var: biased
  var = fmaxf(var, 0.f);
  float rstd = rsqrtf(var + 1e-5f);
  int c = tid * 4;
  float xa[4] = {xv.x, xv.y, xv.z, xv.w};
  bf16x4 ov;
#pragma unroll
  for (int j = 0; j < 4; j++) {
    float wj = loadf(w, (size_t)woff + c + j, fp32m);
    float bj = loadf(bb, (size_t)woff + c + j, fp32m);
    ov[j] = (bf16_t)((xa[j] - mean) * rstd * wj + bj);
  }
  *(bf16x4*)(out + (size_t)row * D_ + c) = ov;
}

// ---------------------------------------------------------------- gelu
__device__ inline float gelu_f(float v) {
  return 0.5f * v * (1.f + erff(v * 0.70710678118654752f));
}

// ---------------------------------------------------------------- tiled MFMA GEMM (bf16 weights in ws)
// C = A @ W^T. 2-deep prefetch pipeline: double-buffered LDS, counted
// s_waitcnt vmcnt(NL) (never 0 in steady state), raw s_barrier (no compiler
// vmcnt(0) drain), setprio(1) around MFMA cluster. Loads for tile t+2 are
// issued right after the last read of their buffer; loads for tile t are
// waited ~2 iterations after issue.
__device__ inline void gload16(void* lds, const void* g) {
  __builtin_amdgcn_global_load_lds(
      (__attribute__((address_space(1))) void*)(g),
      (__attribute__((address_space(3))) void*)(lds), 16, 0, 0);
}

template<int BM, int BN>
__global__ __launch_bounds__(256) void gemm_t(
    const bf16_t* __restrict__ A, const bf16_t* __restrict__ W,
    const void* __restrict__ bias, size_t boff, const float* __restrict__ res,
    bf16_t* __restrict__ outb, float* __restrict__ outf, void* __restrict__ outx,
    const int* __restrict__ modep, int M, int N, int K, int dogelu, int mshift)
{
  constexpr int MT = BM / 32, NT = BN / 32;   // frags per wave
  constexpr int NL = BM / 64 + BN / 64;       // gload16 per thread per K-tile
  __shared__ __align__(16) bf16_t As[2][BM * 32];
  __shared__ __align__(16) bf16_t Bs[2][BN * 32];
  int fp32m = *modep;
  int tid = threadIdx.x;
  int lane = tid & 63, wid = tid >> 6;
  int wm = wid & 1, wn = wid >> 1;
  // ---- bijective XCD remap (assumes block i -> XCD i%8)
  int nwg = gridDim.x, bid = blockIdx.x;
  int qq = nwg >> 3, rr = nwg & 7;
  int xcd = bid & 7, ii = bid >> 3;
  int wg = (xcd < rr ? xcd * (qq + 1) : rr * (qq + 1) + (xcd - rr) * qq) + ii;
  int m0 = (wg & ((1 << mshift) - 1)) * BM;
  int n0 = (wg >> mshift) * BN;
  int ln15 = lane & 15, q4 = lane >> 4;
  int srow = tid >> 2, scol = (tid & 3) * 8;
  const bf16_t* Ag[BM / 64];
  const bf16_t* Wg[BN / 64];
#pragma unroll
  for (int hh = 0; hh < BM / 64; hh++)
    Ag[hh] = A + (size_t)(m0 + hh * 64 + srow) * K + scol;
#pragma unroll
  for (int hh = 0; hh < BN / 64; hh++)
    Wg[hh] = W + (size_t)(n0 + hh * 64 + srow) * K + scol;

  auto stage = [&](int t, int buf) {
    int k0 = t * 32;
#pragma unroll
    for (int hh = 0; hh < BM / 64; hh++)
      gload16(&As[buf][hh * 2048 + tid * 8], Ag[hh] + k0);
#pragma unroll
    for (int hh = 0; hh < BN / 64; hh++)
      gload16(&Bs[buf][hh * 2048 + tid * 8], Wg[hh] + k0);
  };

  int ktiles = K / 32;
  stage(0, 0);
  if (ktiles > 1) stage(1, 1);
  floatx4 acc[MT][NT] = {};
  for (int t = 0; t < ktiles; ++t) {
    int cur = t & 1;
    // wait own tile-t loads (tile t+1's NL may stay in flight)
    if (t + 1 < ktiles)
      asm volatile("s_waitcnt vmcnt(%0)" :: "i"(NL) : "memory");
    else
      asm volatile("s_waitcnt vmcnt(0)" ::: "memory");
    __builtin_amdgcn_s_barrier();          // all waves' tile-t portions in LDS
    asm volatile("" ::: "memory");         // pin LDS reads below the barrier
    bf16x8 a[MT], b[NT];
#pragma unroll
    for (int i = 0; i < MT; i++)
      a[i] = *(const bf16x8*)&As[cur][(wm * (BM / 2) + i * 16 + ln15) * 32 + q4 * 8];
#pragma unroll
    for (int j = 0; j < NT; j++)
      b[j] = *(const bf16x8*)&Bs[cur][(wn * (BN / 2) + j * 16 + ln15) * 32 + q4 * 8];
    __builtin_amdgcn_s_setprio(1);
#pragma unroll
    for (int mt = 0; mt < MT; mt++)
#pragma unroll
      for (int nt = 0; nt < NT; nt++)
        acc[mt][nt] = __builtin_amdgcn_mfma_f32_16x16x32_bf16(a[mt], b[nt], acc[mt][nt], 0, 0, 0);
    __builtin_amdgcn_s_setprio(0);
    asm volatile("" ::: "memory");         // pin LDS reads above barrier2
    __builtin_amdgcn_s_barrier();          // all waves done reading buf[cur]
    if (t + 2 < ktiles) stage(t + 2, cur); // refill freed buffer
  }
#pragma unroll
  for (int mt = 0; mt < MT; mt++)
#pragma unroll
    for (int nt = 0; nt < NT; nt++) {
      int col = n0 + wn * (BN / 2) + nt * 16 + ln15;
      float bv = bias ? loadf(bias, boff + col, fp32m) : 0.f;
#pragma unroll
      for (int r = 0; r < 4; r++) {
        int row = m0 + wm * (BM / 2) + mt * 16 + q4 * 4 + r;
        float v = acc[mt][nt][r] + bv;
        if (dogelu) v = gelu_f(v);
        size_t o = (size_t)row * N + col;
        if (res) v += res[o];
        if (outf) outf[o] = v;
        if (outb) outb[o] = (bf16_t)v;
        if (outx) {
          if (fp32m) ((float*)outx)[o] = v;
          else ((bf16_t*)outx)[o] = (bf16_t)v;
        }
      }
    }
}

// ---------------------------------------------------------------- legacy 64x64 GEMM (fallback, dual-dtype W)
__global__ __launch_bounds__(256) void gemm_bt(
    const bf16_t* __restrict__ A, const void* __restrict__ W, size_t woffs,
    const void* __restrict__ bias, size_t boff, const float* __restrict__ res,
    bf16_t* __restrict__ outb, float* __restrict__ outf, void* __restrict__ outx,
    const int* __restrict__ modep, int M, int N, int K, int dogelu)
{
  __shared__ __align__(16) bf16_t As[64][40];
  __shared__ __align__(16) bf16_t Bs[64][40];
  int fp32m = *modep;
  int tid = threadIdx.x;
  int lane = tid & 63, wid = tid >> 6;
  int wm = wid & 1, wn = wid >> 1;
  int m0 = blockIdx.y * 64, n0 = blockIdx.x * 64;
  int srow = tid >> 2, scol = (tid & 3) * 8;
  const bf16_t* Ap = A + (size_t)(m0 + srow) * K + scol;
  size_t wrow = woffs + (size_t)(n0 + srow) * K + scol;
  floatx4 acc[2][2] = {};
  int ln15 = lane & 15, q4 = lane >> 4;
  for (int k0 = 0; k0 < K; k0 += 32) {
    __syncthreads();
    *(bf16x8*)&As[srow][scol] = *(const bf16x8*)(Ap + k0);
    *(bf16x8*)&Bs[srow][scol] = load8(W, wrow + k0, fp32m);
    __syncthreads();
    bf16x8 a0 = *(const bf16x8*)&As[wm * 32 + ln15][q4 * 8];
    bf16x8 a1 = *(const bf16x8*)&As[wm * 32 + 16 + ln15][q4 * 8];
    bf16x8 b0 = *(const bf16x8*)&Bs[wn * 32 + ln15][q4 * 8];
    bf16x8 b1 = *(const bf16x8*)&Bs[wn * 32 + 16 + ln15][q4 * 8];
    acc[0][0] = __builtin_amdgcn_mfma_f32_16x16x32_bf16(a0, b0, acc[0][0], 0, 0, 0);
    acc[0][1] = __builtin_amdgcn_mfma_f32_16x16x32_bf16(a0, b1, acc[0][1], 0, 0, 0);
    acc[1][0] = __builtin_amdgcn_mfma_f32_16x16x32_bf16(a1, b0, acc[1][0], 0, 0, 0);
    acc[1][1] = __builtin_amdgcn_mfma_f32_16x16x32_bf16(a1, b1, acc[1][1], 0, 0, 0);
  }
#pragma unroll
  for (int mt = 0; mt < 2; mt++)
#pragma unroll
    for (int nt = 0; nt < 2; nt++) {
      int col = n0 + wn * 32 + nt * 16 + ln15;
      float bv = bias ? loadf(bias, boff + col, fp32m) : 0.f;
#pragma unroll
      for (int r = 0; r < 4; r++) {
        int row = m0 + wm * 32 + mt * 16 + q4 * 4 + r;
        float v = acc[mt][nt][r] + bv;
        if (dogelu) v = gelu_f(v);
        size_t o = (size_t)row * N + col;
        if (res) v += res[o];
        if (outf) outf[o] = v;
        if (outb) outb[o] = (bf16_t)v;
        if (outx) {
          if (fp32m) ((float*)outx)[o] = v;
          else ((bf16_t*)outx)[o] = (bf16_t)v;
        }
      }
    }
}

// ---------------------------------------------------------------- MFMA flash attention (muP 1/DH scale)
__global__ __launch_bounds__(256) void attn_mfma(
    const bf16_t* __restrict__ qkv, bf16_t* __restrict__ y)
{
  __shared__ __align__(16) bf16_t Ks[64][72];        // [tok][d], +8 pad
  __shared__ __align__(16) bf16_t Vt[64][72];        // [d][tok^swz], +8 pad
  __shared__ __align__(16) bf16_t Ps[4][16][72];     // per-wave P
  int tid = threadIdx.x;
  int lane = tid & 63, w = tid >> 6;
  int ln15 = lane & 15, g = lane >> 4;
  // heavy-first, paired scheduling: slot i gets qb=15-j, slot i+256 gets qb=j
  int idxb = blockIdx.x;
  int phase = idxb >> 8, slot = idxb & 255;
  int bh = slot >> 3, jj = slot & 7;
  int qb = phase ? jj : (15 - jj);
  int b = bh >> 4, h = bh & 15;
  int q0 = qb * 64;
  int qrow = q0 + w * 16;          // wave's q base
  const bf16_t* kp = qkv + 1024;
  const bf16_t* vp = qkv + 2048;
  // Q fragments (held in registers for the whole block)
  bf16x8 qa0, qa1;
  {
    size_t base = ((size_t)(b * T_ + qrow + ln15)) * 3072 + h * 64 + g * 8;
    qa0 = *(const bf16x8*)(qkv + base);
    qa1 = *(const bf16x8*)(qkv + base + 32);
  }
  floatx4 o[4] = {};               // O accum: d-ntiles, C-layout
  float m_i[4], l_i[4];
#pragma unroll
  for (int r = 0; r < 4; r++) { m_i[r] = -__builtin_inff(); l_i[r] = 0.f; }
  int ntile = qb + 1;
  int sr = tid >> 2, sc = (tid & 3) * 16;   // staging coords
  for (int it = 0; it < ntile; it++) {
    int k0 = it * 64;
    __syncthreads();   // previous tile's LDS reads done
    size_t gb = ((size_t)(b * T_ + k0 + sr)) * 3072 + h * 64 + sc;
    bf16x8 kv0 = *(const bf16x8*)(kp + gb);
    bf16x8 kv1 = *(const bf16x8*)(kp + gb + 8);
    bf16x8 vv0 = *(const bf16x8*)(vp + gb);
    bf16x8 vv1 = *(const bf16x8*)(vp + gb + 8);
    *(bf16x8*)&Ks[sr][sc] = kv0;
    *(bf16x8*)&Ks[sr][sc + 8] = kv1;
#pragma unroll
    for (int e = 0; e < 8; e++) {
      int d0 = sc + e, d1 = sc + 8 + e;
      Vt[d0][sr ^ (((d0 >> 3) & 7) << 3)] = vv0[e];
      Vt[d1][sr ^ (((d1 >> 3) & 7) << 3)] = vv1[e];
    }
    __syncthreads();
    // S = Q @ K^T  (4 n-tiles of 16 k-cols, 2 k-steps over d)
    floatx4 s[4] = {};
#pragma unroll
    for (int nt = 0; nt < 4; nt++) {
      bf16x8 b0 = *(const bf16x8*)&Ks[nt * 16 + ln15][g * 8];
      bf16x8 b1 = *(const bf16x8*)&Ks[nt * 16 + ln15][32 + g * 8];
      s[nt] = __builtin_amdgcn_mfma_f32_16x16x32_bf16(qa0, b0, s[nt], 0, 0, 0);
      s[nt] = __builtin_amdgcn_mfma_f32_16x16x32_bf16(qa1, b1, s[nt], 0, 0, 0);
    }
    int last = (it == ntile - 1);
    // scale + causal mask + per-row max
    float p[4][4];
    float mt[4];
#pragma unroll
    for (int r = 0; r < 4; r++) mt[r] = -__builtin_inff();
#pragma unroll
    for (int nt = 0; nt < 4; nt++)
#pragma unroll
      for (int r = 0; r < 4; r++) {
        float sv = s[nt][r] * 0.015625f;   // muP 1/d_head
        if (last && (k0 + nt * 16 + ln15) > (qrow + g * 4 + r))
          sv = -__builtin_inff();
        p[nt][r] = sv;
        mt[r] = fmaxf(mt[r], sv);
      }
#pragma unroll
    for (int off = 1; off < 16; off <<= 1)
#pragma unroll
      for (int r = 0; r < 4; r++) mt[r] = fmaxf(mt[r], __shfl_xor(mt[r], off));
    float alpha[4];
#pragma unroll
    for (int r = 0; r < 4; r++) {
      float mn = fmaxf(m_i[r], mt[r]);
      alpha[r] = __expf(m_i[r] - mn);   // exp(-inf)=0 on first tile
      m_i[r] = mn;
    }
    // P = exp(S - m), row-sum, write to per-wave LDS for layout conversion
    float rs[4] = {0.f, 0.f, 0.f, 0.f};
#pragma unroll
    for (int nt = 0; nt < 4; nt++)
#pragma unroll
      for (int r = 0; r < 4; r++) {
        float pv = __expf(p[nt][r] - m_i[r]);
        rs[r] += pv;
        Ps[w][g * 4 + r][nt * 16 + ln15] = (bf16_t)pv;
      }
#pragma unroll
    for (int off = 1; off < 16; off <<= 1)
#pragma unroll
      for (int r = 0; r < 4; r++) rs[r] += __shfl_xor(rs[r], off);
#pragma unroll
    for (int r = 0; r < 4; r++) l_i[r] = l_i[r] * alpha[r] + rs[r];
#pragma unroll
    for (int nt = 0; nt < 4; nt++)
#pragma unroll
      for (int r = 0; r < 4; r++) o[nt][r] *= alpha[r];
    // O += P @ V  (P A-frags from LDS, V B-frags from transposed Vt)
#pragma unroll
    for (int ks = 0; ks < 2; ks++) {
      bf16x8 pa = *(const bf16x8*)&Ps[w][ln15][ks * 32 + g * 8];
#pragma unroll
      for (int nt = 0; nt < 4; nt++) {
        int d = nt * 16 + ln15;
        bf16x8 vb = *(const bf16x8*)&Vt[d][(ks * 32 + g * 8) ^ (((d >> 3) & 7) << 3)];
        o[nt] = __builtin_amdgcn_mfma_f32_16x16x32_bf16(pa, vb, o[nt], 0, 0, 0);
      }
    }
  }
  // epilogue: normalize and store
#pragma unroll
  for (int nt = 0; nt < 4; nt++)
#pragma unroll
    for (int r = 0; r < 4; r++) {
      size_t orow = (size_t)(b * T_ + qrow + g * 4 + r) * D_ + h * 64 + nt * 16 + ln15;
      y[orow] = (bf16_t)(o[nt][r] / l_i[r]);
    }
}

// ---------------------------------------------------------------- legacy scalar flash attention (fallback)
__global__ __launch_bounds__(256) void attn_kernel(
    const bf16_t* __restrict__ q, const bf16_t* __restrict__ k,
    const bf16_t* __restrict__ v, bf16_t* __restrict__ y, int stride)
{
  __shared__ float Kt[64][65];
  __shared__ float Vt[64][65];
  __shared__ float qs[4][64];
  __shared__ float ps[4][64];
  int tid = threadIdx.x;
  int lane = tid & 63, w = tid >> 6;
  int blk = blockIdx.x;
  int tqblk = blk & 255;
  int bh = blk >> 8;
  int b = bh >> 4, hh = bh & 15;
  int tq_base = tqblk * 4;
  int tq = tq_base + w;
  size_t qrow = ((size_t)(b * T_ + tq)) * stride + hh * DH_;
  qs[w][lane] = (float)q[qrow + lane];
  float m_i = -INFINITY, l_i = 0.f, acc = 0.f;
  int ntiles = (tq_base >> 6) + 1;
  int lr = tid >> 2, lc = (tid & 3) * 16;
  for (int it = 0; it < ntiles; it++) {
    int tk0 = it * 64;
    __syncthreads();
    size_t gbase = ((size_t)(b * T_ + tk0 + lr)) * stride + hh * DH_ + lc;
    bf16x8 kv0 = *(const bf16x8*)(k + gbase);
    bf16x8 kv1 = *(const bf16x8*)(k + gbase + 8);
    bf16x8 vv0 = *(const bf16x8*)(v + gbase);
    bf16x8 vv1 = *(const bf16x8*)(v + gbase + 8);
#pragma unroll
    for (int j = 0; j < 8; j++) {
      Kt[lr][lc + j] = (float)kv0[j];
      Kt[lr][lc + 8 + j] = (float)kv1[j];
      Vt[lr][lc + j] = (float)vv0[j];
      Vt[lr][lc + 8 + j] = (float)vv1[j];
    }
    __syncthreads();
    int tk = tk0 + lane;
    float s = -INFINITY;
    if (tk <= tq) {
      float a = 0.f;
#pragma unroll
      for (int d = 0; d < 64; d++) a += qs[w][d] * Kt[lane][d];
      s = a * (1.f / 64.f);
    }
    float mt = s;
#pragma unroll
    for (int off = 32; off; off >>= 1) mt = fmaxf(mt, __shfl_xor(mt, off));
    float mnew = fmaxf(m_i, mt);
    float alpha = (m_i == -INFINITY) ? 0.f : expf(m_i - mnew);
    float p = (tk <= tq) ? expf(s - mnew) : 0.f;
    float psum = p;
#pragma unroll
    for (int off = 32; off; off >>= 1) psum += __shfl_xor(psum, off);
    l_i = l_i * alpha + psum;
    ps[w][lane] = p;
    float pv = 0.f;
#pragma unroll
    for (int j = 0; j < 64; j++) pv += ps[w][j] * Vt[j][lane];
    acc = acc * alpha + pv;
    m_i = mnew;
  }
  y[((size_t)(b * T_ + tq)) * D_ + hh * DH_ + lane] = (bf16_t)(acc / l_i);
}

// ---------------------------------------------------------------- host
// tile selection: head/fc1 -> 128x128; qkv -> 64x128; proj/fc2 -> 64x64.
// mshift = log2(M/BM); M=2048 always.
template<int BM, int BN>
static inline void launch_gemm_t(const bf16_t* A, const bf16_t* W,
                                 const void* bias, size_t boff, const float* res,
                                 bf16_t* outb, float* outf, void* outx,
                                 const int* modep, int M, int N, int K,
                                 int dogelu, hipStream_t s)
{
  int nMB = M / BM;
  int mshift = (nMB == 16) ? 4 : ((nMB == 32) ? 5 : 31 - __builtin_clz(nMB));
  int nwg = nMB * (N / BN);
  gemm_t<BM, BN><<<dim3(nwg), dim3(256), 0, s>>>(
      A, W, bias, boff, res, outb, outf, outx, modep, M, N, K, dogelu, mshift);
}

static inline void launch_gemm_old(const bf16_t* A, const void* W, size_t woffs,
                                   const void* bias, size_t boff, const float* res,
                                   bf16_t* outb, float* outf, void* outx,
                                   const int* modep, int M, int N, int K,
                                   int dogelu, hipStream_t s)
{
  dim3 g(N / 64, M / 64);
  gemm_bt<<<g, dim3(256), 0, s>>>(A, W, woffs, bias, boff, res, outb, outf,
                                  outx, modep, M, N, K, dogelu);
}

// workspace layout (new path)
#define OFF_X      256ull
#define OFF_H      8388864ull
#define OFF_QKV    12583168ull
#define OFF_Y      25166080ull
#define OFF_HF     29360384ull
#define OFF_WQKV   46137600ull
#define OFF_WPROJ  83886336ull
#define OFF_WFC1   96469248ull
#define OFF_WFC2   146800896ull
#define OFF_WHEAD  197132544ull
#define REQ_WS     262668544ull

extern "C" void kernel_launch(void* const* d_in, const int* in_sizes, int n_in,
                              void* d_out, int out_size, void* d_ws, size_t ws_size,
                              hipStream_t stream)
{
  (void)in_sizes; (void)n_in; (void)out_size;
  const int* idx      = (const int*)d_in[0];
  const void* tok_emb = d_in[1];
  const void* pos_emb = d_in[2];
  const void* ln1_w   = d_in[3];
  const void* ln1_b   = d_in[4];
  const void* wq      = d_in[5];
  const void* wk      = d_in[6];
  const void* wv      = d_in[7];
  const void* wproj   = d_in[8];
  const void* ln2_w   = d_in[9];
  const void* ln2_b   = d_in[10];
  const void* fc1_w   = d_in[11];
  const void* fc1_b   = d_in[12];
  const void* fc2_w   = d_in[13];
  const void* fc2_b   = d_in[14];
  const void* lnf_w   = d_in[15];
  const void* lnf_b   = d_in[16];
  const void* head_w  = d_in[17];

  char* ws = (char*)d_ws;
  int* modep = (int*)ws;
  detect_kernel<<<1, 256, 0, stream>>>((const unsigned short*)tok_emb, modep);

  if (ws_size >= REQ_WS) {
    // ---------------- fast path: bf16 weights in ws + tiled gload_lds GEMM
    float*  x   = (float*)(ws + OFF_X);
    bf16_t* h   = (bf16_t*)(ws + OFF_H);
    bf16_t* qkv = (bf16_t*)(ws + OFF_QKV);   // [NTOK][3072]
    bf16_t* yb  = (bf16_t*)(ws + OFF_Y);
    bf16_t* hf  = (bf16_t*)(ws + OFF_HF);
    bf16_t* wqkvb = (bf16_t*)(ws + OFF_WQKV);   // [L][3][D][D]
    bf16_t* wprjb = (bf16_t*)(ws + OFF_WPROJ);  // [L][D][D]
    bf16_t* wfc1b = (bf16_t*)(ws + OFF_WFC1);   // [L][F][D]
    bf16_t* wfc2b = (bf16_t*)(ws + OFF_WFC2);   // [L][D][F]
    bf16_t* whedb = (bf16_t*)(ws + OFF_WHEAD);  // [V][D]

    convqkv_kernel<<<9216, 256, 0, stream>>>(wq, wk, wv, wqkvb, modep);
    convflat_kernel<<<3072, 256, 0, stream>>>(wproj, wprjb, modep, (long)L_ * D_ * D_);
    convflat_kernel<<<12288, 256, 0, stream>>>(fc1_w, wfc1b, modep, (long)L_ * F_ * D_);
    convflat_kernel<<<12288, 256, 0, stream>>>(fc2_w, wfc2b, modep, (long)L_ * D_ * F_);
    convflat_kernel<<<16000, 256, 0, stream>>>(head_w, whedb, modep, (long)V_ * D_);

    embed_kernel<<<NTOK, 256, 0, stream>>>(idx, tok_emb, pos_emb, x, modep);

    for (int l = 0; l < L_; l++) {
      size_t wd = (size_t)l * D_ * D_;
      size_t wf = (size_t)l * F_ * D_;
      ln_kernel<<<NTOK, 256, 0, stream>>>(x, ln1_w, ln1_b, h, modep, l * D_);
      launch_gemm_t<64, 128>(h, wqkvb + (size_t)l * 3 * D_ * D_, nullptr, 0,
                             nullptr, qkv, nullptr, nullptr, modep,
                             NTOK, 3 * D_, D_, 0, stream);
      attn_mfma<<<512, 256, 0, stream>>>(qkv, yb);
      launch_gemm_t<64, 64>(yb, wprjb + wd, nullptr, 0, x, nullptr, x, nullptr,
                            modep, NTOK, D_, D_, 0, stream);
      ln_kernel<<<NTOK, 256, 0, stream>>>(x, ln2_w, ln2_b, h, modep, l * D_);
      launch_gemm_t<128, 128>(h, wfc1b + wf, fc1_b, (size_t)l * F_, nullptr, hf,
                              nullptr, nullptr, modep, NTOK, F_, D_, 1, stream);
      launch_gemm_t<64, 64>(hf, wfc2b + wf, fc2_b, (size_t)l * D_, x, nullptr, x,
                            nullptr, modep, NTOK, D_, F_, 0, stream);
    }

    ln_kernel<<<NTOK, 256, 0, stream>>>(x, lnf_w, lnf_b, h, modep, 0);
    launch_gemm_t<128, 128>(h, whedb, nullptr, 0, nullptr, nullptr, nullptr,
                            d_out, modep, NTOK, V_, D_, 0, stream);
  } else {
    // ---------------- fallback: previous verified path
    float*  x  = (float*)(ws + 256);
    bf16_t* h  = (bf16_t*)(ws + 8388864);
    bf16_t* qb = (bf16_t*)(ws + 12583168);
    bf16_t* kb = (bf16_t*)(ws + 16777472);
    bf16_t* vb = (bf16_t*)(ws + 20971776);
    bf16_t* yb = (bf16_t*)(ws + 25166080);
    bf16_t* hf = (bf16_t*)(ws + 29360384);

    embed_kernel<<<NTOK, 256, 0, stream>>>(idx, tok_emb, pos_emb, x, modep);

    for (int l = 0; l < L_; l++) {
      size_t wd = (size_t)l * D_ * D_;
      size_t wf = (size_t)l * F_ * D_;
      ln_kernel<<<NTOK, 256, 0, stream>>>(x, ln1_w, ln1_b, h, modep, l * D_);
      launch_gemm_old(h, wq, wd, nullptr, 0, nullptr, qb, nullptr, nullptr,
                      modep, NTOK, D_, D_, 0, stream);
      launch_gemm_old(h, wk, wd, nullptr, 0, nullptr, kb, nullptr, nullptr,
                      modep, NTOK, D_, D_, 0, stream);
      launch_gemm_old(h, wv, wd, nullptr, 0, nullptr, vb, nullptr, nullptr,
                      modep, NTOK, D_, D_, 0, stream);
      attn_kernel<<<B_ * H_ * (T_ / 4), 256, 0, stream>>>(qb, kb, vb, yb, D_);
      launch_gemm_old(yb, wproj, wd, nullptr, 0, x, nullptr, x, nullptr,
                      modep, NTOK, D_, D_, 0, stream);
      ln_kernel<<<NTOK, 256, 0, stream>>>(x, ln2_w, ln2_b, h, modep, l * D_);
      launch_gemm_old(h, fc1_w, wf, fc1_b, (size_t)l * F_, nullptr, hf, nullptr,
                      nullptr, modep, NTOK, F_, D_, 1, stream);
      launch_gemm_old(hf, fc2_w, wf, fc2_b, (size_t)l * D_, x, nullptr, x,
                      nullptr, modep, NTOK, D_, F_, 0, stream);
    }

    ln_kernel<<<NTOK, 256, 0, stream>>>(x, lnf_w, lnf_b, h, modep, 0);
    launch_gemm_old(h, head_w, 0, nullptr, 0, nullptr, nullptr, nullptr, d_out,
                    modep, NTOK, V_, D_, 0, stream);
  }
}